// Round 1
// baseline (604.047 us; speedup 1.0000x reference)
//
#include <hip/hip_runtime.h>
#include <hip/hip_bf16.h>

#define NN 50000
#define NE 600000
// feature dims: in=128, hid=128, policy hidden=64, out=2

typedef __attribute__((ext_vector_type(8))) short short8;   // 8 bf16 (4 VGPRs)
typedef __attribute__((ext_vector_type(4))) float floatx4;  // 4 f32 acc

// ---------------- utility kernels ----------------

__global__ void k_zero_init(int* __restrict__ count, int* __restrict__ flag) {
    int i = blockIdx.x * blockDim.x + threadIdx.x;
    if (i < NN) count[i] = 0;
    if (i == 0) *flag = 0;
}

// detect int32 vs int64 edge_index layout: int64 => odd 32-bit words all zero
__global__ void k_detect(const int* __restrict__ raw, int* __restrict__ flag) {
    int i = threadIdx.x;
    int any = 0;
    for (int j = i; j < 1024; j += 256) any |= raw[2 * j + 1];
    if (any) atomicOr(flag, 1);  // flag=1 -> int32 layout
}

__global__ void k_extract(const int* __restrict__ raw, const int* __restrict__ flag,
                          int* __restrict__ src32, int* __restrict__ dst32) {
    int e = blockIdx.x * blockDim.x + threadIdx.x;
    if (e >= NE) return;
    if (*flag) {
        src32[e] = raw[e];
        dst32[e] = raw[NE + e];
    } else {
        const long long* r64 = (const long long*)raw;
        src32[e] = (int)r64[e];
        dst32[e] = (int)r64[NE + e];
    }
}

__global__ void k_cvt_bf16(const float* __restrict__ in, __hip_bfloat16* __restrict__ out,
                           int n, int do_relu) {
    int i = blockIdx.x * blockDim.x + threadIdx.x;
    if (i >= n) return;
    float v = in[i];
    if (do_relu) v = v > 0.f ? v : 0.f;
    out[i] = __float2bfloat16(v);
}

__global__ void k_count(const int* __restrict__ dst, int* __restrict__ count) {
    int e = blockIdx.x * blockDim.x + threadIdx.x;
    if (e < NE) atomicAdd(&count[dst[e]], 1);
}

// two-level inclusive scan of count[NN]
__global__ void k_scan_block(const int* __restrict__ count, int* __restrict__ tmp,
                             int* __restrict__ bsums) {
    __shared__ int s[512];
    int tid = threadIdx.x;
    int i = blockIdx.x * 512 + tid;
    s[tid] = (i < NN) ? count[i] : 0;
    __syncthreads();
    for (int off = 1; off < 512; off <<= 1) {
        int t = (tid >= off) ? s[tid - off] : 0;
        __syncthreads();
        s[tid] += t;
        __syncthreads();
    }
    if (i < NN) tmp[i] = s[tid];
    if (tid == 511) bsums[blockIdx.x] = s[511];
}

__global__ void k_scan_sums(int* __restrict__ bsums, int nb) {
    __shared__ int s[128];
    int tid = threadIdx.x;
    int v = (tid < nb) ? bsums[tid] : 0;
    s[tid] = v;
    __syncthreads();
    for (int off = 1; off < 128; off <<= 1) {
        int t = (tid >= off) ? s[tid - off] : 0;
        __syncthreads();
        s[tid] += t;
        __syncthreads();
    }
    if (tid < nb) bsums[tid] = s[tid] - v;  // exclusive
}

__global__ void k_finalize_scan(const int* __restrict__ tmp, const int* __restrict__ count,
                                const int* __restrict__ bsums, int* __restrict__ rowptr,
                                int* __restrict__ cursor, float* __restrict__ deg) {
    int i = blockIdx.x * blockDim.x + threadIdx.x;
    if (i >= NN) return;
    int incl = tmp[i] + bsums[i >> 9];
    rowptr[i + 1] = incl;
    cursor[i] = incl - count[i];
    deg[i] = 1.0f;  // self-loop weight
    if (i == 0) rowptr[0] = 0;
}

__global__ void k_fill(const int* __restrict__ dst, int* __restrict__ cursor,
                       int* __restrict__ eid) {
    int e = blockIdx.x * blockDim.x + threadIdx.x;
    if (e < NE) {
        int pos = atomicAdd(&cursor[dst[e]], 1);
        eid[pos] = e;
    }
}

__global__ void k_dinv(float* __restrict__ deg) {
    int i = blockIdx.x * blockDim.x + threadIdx.x;
    if (i < NN) deg[i] = rsqrtf(deg[i]);  // deg >= 1 always
}

// ---------------- policy MLP: edge weights + deg accumulation ----------------
// H[16 x 64] = cat[16 x 256] * Wp1^T ; ew = sigmoid(relu(H + b1) . w2 + b2)
__global__ __launch_bounds__(256) void k_policy(
    const __hip_bfloat16* __restrict__ xb, const __hip_bfloat16* __restrict__ wp1b,
    const float* __restrict__ bp1, const float* __restrict__ wp2,
    const float* __restrict__ bp2, const int* __restrict__ src,
    const int* __restrict__ dst, float* __restrict__ ew, float* __restrict__ deg) {
    const int lane = threadIdx.x & 63;
    const int wave = threadIdx.x >> 6;
    const int col = lane & 15;
    const int quad = lane >> 4;

    // B frags in registers: B[k][n] = Wp1[n][k]; 16B contiguous per frag
    short8 bfrag[8][4];
    const short* wp = (const short*)wp1b;
#pragma unroll
    for (int tt = 0; tt < 4; ++tt) {
        int row = tt * 16 + col;
#pragma unroll
        for (int kk = 0; kk < 8; ++kk)
            bfrag[kk][tt] = *(const short8*)(wp + row * 256 + kk * 32 + quad * 8);
    }
    float w2v[4], b1v[4];
#pragma unroll
    for (int tt = 0; tt < 4; ++tt) {
        w2v[tt] = wp2[tt * 16 + col];
        b1v[tt] = bp1[tt * 16 + col];
    }
    float b2 = bp2[0];

    int tile = blockIdx.x * 4 + wave;  // 37500 tiles exactly
    int ebase = tile * 16;
    int e_m = ebase + col;  // A-operand row m = col
    int sm = src[e_m], dm = dst[e_m];
    const short* xs = (const short*)xb;

    floatx4 acc[4];
#pragma unroll
    for (int t = 0; t < 4; ++t) acc[t] = (floatx4){0.f, 0.f, 0.f, 0.f};

#pragma unroll
    for (int kk = 0; kk < 8; ++kk) {
        // cols 0..127 from x[src], 128..255 from x[dst]; kk<4 stays in src half
        const short* rowp = (kk < 4) ? (xs + sm * 128 + kk * 32 + quad * 8)
                                     : (xs + dm * 128 + (kk - 4) * 32 + quad * 8);
        short8 afrag = *(const short8*)rowp;
#pragma unroll
        for (int tt = 0; tt < 4; ++tt)
            acc[tt] = __builtin_amdgcn_mfma_f32_16x16x32_bf16(afrag, bfrag[kk][tt], acc[tt], 0, 0, 0);
    }
    // layer 2: per-edge reduction over 64 hidden (16 lanes x 4 tiles)
    float part[4] = {0.f, 0.f, 0.f, 0.f};
#pragma unroll
    for (int tt = 0; tt < 4; ++tt) {
#pragma unroll
        for (int r = 0; r < 4; ++r) {
            float h = acc[tt][r] + b1v[tt];
            h = h > 0.f ? h : 0.f;
            part[r] += h * w2v[tt];
        }
    }
#pragma unroll
    for (int off = 1; off < 16; off <<= 1) {
#pragma unroll
        for (int r = 0; r < 4; ++r) part[r] += __shfl_xor(part[r], off, 64);
    }
    if (col < 4) {  // lane col==r writes edge m = quad*4 + r
        int e = ebase + quad * 4 + col;
        float v = 1.f / (1.f + __expf(-(part[col] + b2)));
        ew[e] = v;
        atomicAdd(&deg[dst[e]], v);
    }
}

// ---------------- GCN feature transform: xl = A_in * W^T, + agg init ----------------
__global__ __launch_bounds__(256) void k_gemm(
    const __hip_bfloat16* __restrict__ A, const __hip_bfloat16* __restrict__ Wb,
    const float* __restrict__ bias, const float* __restrict__ dinv,
    __hip_bfloat16* __restrict__ xlb, float* __restrict__ agg) {
    const int lane = threadIdx.x & 63;
    const int wave = threadIdx.x >> 6;
    const int col = lane & 15;
    const int quad = lane >> 4;

    short8 bfrag[4][8];
    const short* wp = (const short*)Wb;
#pragma unroll
    for (int tt = 0; tt < 8; ++tt) {
        int row = tt * 16 + col;
#pragma unroll
        for (int kk = 0; kk < 4; ++kk)
            bfrag[kk][tt] = *(const short8*)(wp + row * 128 + kk * 32 + quad * 8);
    }
    int tile = blockIdx.x * 4 + wave;
    if (tile >= NN / 16) return;  // 3125 tiles
    int base = tile * 16;
    const short* xs = (const short*)A;

    floatx4 acc[8];
#pragma unroll
    for (int t = 0; t < 8; ++t) acc[t] = (floatx4){0.f, 0.f, 0.f, 0.f};

#pragma unroll
    for (int kk = 0; kk < 4; ++kk) {
        short8 afrag = *(const short8*)(xs + (base + col) * 128 + kk * 32 + quad * 8);
#pragma unroll
        for (int tt = 0; tt < 8; ++tt)
            acc[tt] = __builtin_amdgcn_mfma_f32_16x16x32_bf16(afrag, bfrag[kk][tt], acc[tt], 0, 0, 0);
    }
    float di2[4];
#pragma unroll
    for (int r = 0; r < 4; ++r) {
        float d = dinv[base + quad * 4 + r];
        di2[r] = d * d;
    }
#pragma unroll
    for (int tt = 0; tt < 8; ++tt) {
        int n = tt * 16 + col;
        float bv = bias[n];
#pragma unroll
        for (int r = 0; r < 4; ++r) {
            int row = base + quad * 4 + r;
            float v = acc[tt][r];
            xlb[row * 128 + n] = __float2bfloat16(v);
            agg[row * 128 + n] = bv + di2[r] * v;  // bias + self-loop term
        }
    }
}

// ---------------- edge aggregation: one wave per destination node ----------------
__global__ __launch_bounds__(256) void k_scatter(
    const int* __restrict__ rowptr, const int* __restrict__ eid,
    const int* __restrict__ src, const float* __restrict__ ew,
    const float* __restrict__ dinv, const __hip_bfloat16* __restrict__ xlb,
    float* __restrict__ agg) {
    int wid = (blockIdx.x * blockDim.x + threadIdx.x) >> 6;
    int lane = threadIdx.x & 63;
    if (wid >= NN) return;
    int beg = rowptr[wid], end = rowptr[wid + 1];
    float dn = dinv[wid];
    float a0 = 0.f, a1 = 0.f;
    for (int p = beg; p < end; ++p) {
        int e = eid[p];
        int s = src[e];
        float coef = dinv[s] * ew[e] * dn;
        __hip_bfloat162 v = *(const __hip_bfloat162*)(xlb + s * 128 + lane * 2);
        a0 += coef * __low2float(v);
        a1 += coef * __high2float(v);
    }
    float2* ap = (float2*)(agg + wid * 128 + lane * 2);
    float2 c = *ap;
    c.x += a0;
    c.y += a1;
    *ap = c;
}

// ---------------- output head: sigmoid(relu(agg) @ Wlin^T + blin) ----------------
__global__ __launch_bounds__(256) void k_out(const float* __restrict__ agg,
                                             const float* __restrict__ wlin,
                                             const float* __restrict__ blin,
                                             float* __restrict__ out) {
    int wid = (blockIdx.x * blockDim.x + threadIdx.x) >> 6;
    int lane = threadIdx.x & 63;
    if (wid >= NN) return;
    float v0 = agg[wid * 128 + lane];
    float v1 = agg[wid * 128 + 64 + lane];
    v0 = v0 > 0.f ? v0 : 0.f;
    v1 = v1 > 0.f ? v1 : 0.f;
    float p0 = v0 * wlin[lane] + v1 * wlin[64 + lane];
    float p1 = v0 * wlin[128 + lane] + v1 * wlin[192 + lane];
#pragma unroll
    for (int off = 1; off < 64; off <<= 1) {
        p0 += __shfl_xor(p0, off, 64);
        p1 += __shfl_xor(p1, off, 64);
    }
    if (lane == 0) {
        out[wid * 2 + 0] = 1.f / (1.f + __expf(-(p0 + blin[0])));
        out[wid * 2 + 1] = 1.f / (1.f + __expf(-(p1 + blin[1])));
    }
}

// ---------------- host launcher ----------------

extern "C" void kernel_launch(void* const* d_in, const int* in_sizes, int n_in,
                              void* d_out, int out_size, void* d_ws, size_t ws_size,
                              hipStream_t stream) {
    const float* x = (const float*)d_in[0];
    const int* eidx_raw = (const int*)d_in[1];
    const float* W_p1 = (const float*)d_in[2];
    const float* b_p1 = (const float*)d_in[3];
    const float* W_p2 = (const float*)d_in[4];
    const float* b_p2 = (const float*)d_in[5];
    const float* W1 = (const float*)d_in[6];
    const float* b1 = (const float*)d_in[7];
    const float* W2 = (const float*)d_in[8];
    const float* b2 = (const float*)d_in[9];
    const float* W_lin = (const float*)d_in[10];
    const float* b_lin = (const float*)d_in[11];
    float* out = (float*)d_out;

    char* ws = (char*)d_ws;
    size_t off = 0;
    auto alloc = [&](size_t bytes) -> void* {
        off = (off + 255) & ~(size_t)255;
        void* p = ws + off;
        off += bytes;
        return p;
    };
    float* ew = (float*)alloc(NE * 4);
    float* deg = (float*)alloc(NN * 4);  // becomes dinv in place
    int* rowptr = (int*)alloc((NN + 1) * 4);
    int* cursor = (int*)alloc(NN * 4);
    int* count = (int*)alloc(NN * 4);
    int* flag = (int*)alloc(4);
    int* eid = (int*)alloc(NE * 4);  // also reused as scan tmp before fill
    int* bsums = (int*)alloc(128 * 4);
    int* src32 = (int*)alloc(NE * 4);
    int* dst32 = (int*)alloc(NE * 4);
    __hip_bfloat16* xb = (__hip_bfloat16*)alloc(NN * 128 * 2);
    __hip_bfloat16* xlb = (__hip_bfloat16*)alloc(NN * 128 * 2);
    float* agg = (float*)alloc((size_t)NN * 128 * 4);
    __hip_bfloat16* wp1b = (__hip_bfloat16*)alloc(64 * 256 * 2);
    __hip_bfloat16* w1b = (__hip_bfloat16*)alloc(128 * 128 * 2);
    __hip_bfloat16* w2b = (__hip_bfloat16*)alloc(128 * 128 * 2);
    int* tmp = eid;

    const int TB = 256;
    int gN = (NN + TB - 1) / TB;
    int gE = (NE + TB - 1) / TB;

    k_zero_init<<<gN, TB, 0, stream>>>(count, flag);
    k_detect<<<1, 256, 0, stream>>>(eidx_raw, flag);
    k_extract<<<gE, TB, 0, stream>>>(eidx_raw, flag, src32, dst32);

    k_cvt_bf16<<<(NN * 128 + TB - 1) / TB, TB, 0, stream>>>(x, xb, NN * 128, 0);
    k_cvt_bf16<<<(64 * 256 + TB - 1) / TB, TB, 0, stream>>>(W_p1, wp1b, 64 * 256, 0);
    k_cvt_bf16<<<(128 * 128 + TB - 1) / TB, TB, 0, stream>>>(W1, w1b, 128 * 128, 0);
    k_cvt_bf16<<<(128 * 128 + TB - 1) / TB, TB, 0, stream>>>(W2, w2b, 128 * 128, 0);

    k_count<<<gE, TB, 0, stream>>>(dst32, count);
    k_scan_block<<<98, 512, 0, stream>>>(count, tmp, bsums);
    k_scan_sums<<<1, 128, 0, stream>>>(bsums, 98);
    k_finalize_scan<<<gN, TB, 0, stream>>>(tmp, count, bsums, rowptr, cursor, deg);

    k_policy<<<NE / 16 / 4, TB, 0, stream>>>(xb, wp1b, b_p1, W_p2, b_p2, src32, dst32, ew, deg);
    k_fill<<<gE, TB, 0, stream>>>(dst32, cursor, eid);
    k_dinv<<<gN, TB, 0, stream>>>(deg);

    // layer 1
    k_gemm<<<(NN / 16 + 3) / 4, TB, 0, stream>>>(xb, w1b, b1, deg, xlb, agg);
    k_scatter<<<(NN + 3) / 4, TB, 0, stream>>>(rowptr, eid, src32, ew, deg, xlb, agg);
    // layer 2 (input = relu(agg1) as bf16, reuse xb)
    k_cvt_bf16<<<(NN * 128 + TB - 1) / TB, TB, 0, stream>>>(agg, xb, NN * 128, 1);
    k_gemm<<<(NN / 16 + 3) / 4, TB, 0, stream>>>(xb, w2b, b2, deg, xlb, agg);
    k_scatter<<<(NN + 3) / 4, TB, 0, stream>>>(rowptr, eid, src32, ew, deg, xlb, agg);

    k_out<<<(NN + 3) / 4, TB, 0, stream>>>(agg, W_lin, b_lin, out);
}

// Round 2
// 376.660 us; speedup vs baseline: 1.6037x; 1.6037x over previous
//
#include <hip/hip_runtime.h>
#include <hip/hip_bf16.h>

#define NN 50000
#define NE 600000
// dims: in=128, hid=128, policy hidden=64, out=2

typedef __attribute__((ext_vector_type(8))) short short8;     // 8 bf16 (4 VGPRs)
typedef __attribute__((ext_vector_type(8))) _Float16 half8;   // 8 fp16
typedef __attribute__((ext_vector_type(4))) float floatx4;    // 4 f32 acc

// ---------------- utility kernels ----------------

__global__ void k_zero_init(int* __restrict__ count, int* __restrict__ flag) {
    int i = blockIdx.x * blockDim.x + threadIdx.x;
    if (i < NN) count[i] = 0;
    if (i == 0) *flag = 0;
}

// detect int32 vs int64 edge_index layout: int64 => odd 32-bit words all zero
__global__ void k_detect(const int* __restrict__ raw, int* __restrict__ flag) {
    int i = threadIdx.x;
    int any = 0;
    for (int j = i; j < 1024; j += 256) any |= raw[2 * j + 1];
    if (any) atomicOr(flag, 1);  // flag=1 -> int32 layout
}

// extract src/dst (either layout) + fused degree count
__global__ void k_extract(const int* __restrict__ raw, const int* __restrict__ flag,
                          int* __restrict__ src32, int* __restrict__ dst32,
                          int* __restrict__ count) {
    int e = blockIdx.x * blockDim.x + threadIdx.x;
    if (e >= NE) return;
    int s, d;
    if (*flag) {
        s = raw[e];
        d = raw[NE + e];
    } else {
        const long long* r64 = (const long long*)raw;
        s = (int)r64[e];
        d = (int)r64[NE + e];
    }
    src32[e] = s;
    dst32[e] = d;
    atomicAdd(&count[d], 1);
}

__global__ void k_cvt_bf16(const float* __restrict__ in, __hip_bfloat16* __restrict__ out,
                           int n, int do_relu) {
    int i = blockIdx.x * blockDim.x + threadIdx.x;
    if (i >= n) return;
    float v = in[i];
    if (do_relu) v = v > 0.f ? v : 0.f;
    out[i] = __float2bfloat16(v);
}

// W_cat[128][128] bf16: rows 0-63 = W_p1[:, 0:128], rows 64-127 = W_p1[:, 128:256]
__global__ void k_cvt_wcat(const float* __restrict__ wp1, __hip_bfloat16* __restrict__ out) {
    int i = blockIdx.x * blockDim.x + threadIdx.x;
    if (i >= 128 * 128) return;
    int r = i >> 7, c = i & 127;
    float v = (r < 64) ? wp1[r * 256 + c] : wp1[(r - 64) * 256 + 128 + c];
    out[i] = __float2bfloat16(v);
}

// two-level inclusive scan of count[NN]
__global__ void k_scan_block(const int* __restrict__ count, int* __restrict__ tmp,
                             int* __restrict__ bsums) {
    __shared__ int s[512];
    int tid = threadIdx.x;
    int i = blockIdx.x * 512 + tid;
    s[tid] = (i < NN) ? count[i] : 0;
    __syncthreads();
    for (int off = 1; off < 512; off <<= 1) {
        int t = (tid >= off) ? s[tid - off] : 0;
        __syncthreads();
        s[tid] += t;
        __syncthreads();
    }
    if (i < NN) tmp[i] = s[tid];
    if (tid == 511) bsums[blockIdx.x] = s[511];
}

__global__ void k_scan_sums(int* __restrict__ bsums, int nb) {
    __shared__ int s[128];
    int tid = threadIdx.x;
    int v = (tid < nb) ? bsums[tid] : 0;
    s[tid] = v;
    __syncthreads();
    for (int off = 1; off < 128; off <<= 1) {
        int t = (tid >= off) ? s[tid - off] : 0;
        __syncthreads();
        s[tid] += t;
        __syncthreads();
    }
    if (tid < nb) bsums[tid] = s[tid] - v;  // exclusive
}

__global__ void k_finalize_scan(const int* __restrict__ tmp, const int* __restrict__ count,
                                const int* __restrict__ bsums, int* __restrict__ rowptr,
                                int* __restrict__ cursor, float* __restrict__ deg) {
    int i = blockIdx.x * blockDim.x + threadIdx.x;
    if (i >= NN) return;
    int incl = tmp[i] + bsums[i >> 9];
    rowptr[i + 1] = incl;
    cursor[i] = incl - count[i];
    deg[i] = 1.0f;  // self-loop weight
    if (i == 0) rowptr[0] = 0;
}

__global__ void k_fill(const int* __restrict__ dst, const int* __restrict__ src,
                       int* __restrict__ cursor, int* __restrict__ eid,
                       int* __restrict__ csr_src) {
    int e = blockIdx.x * blockDim.x + threadIdx.x;
    if (e < NE) {
        int pos = atomicAdd(&cursor[dst[e]], 1);
        eid[pos] = e;
        csr_src[pos] = src[e];
    }
}

__global__ void k_dinv(float* __restrict__ deg) {
    int i = blockIdx.x * blockDim.x + threadIdx.x;
    if (i < NN) deg[i] = rsqrtf(deg[i]);  // deg >= 1 always
}

// csr_coef[p] = dinv[src] * ew[e]   (dinv[dst] applied per-node in scatter)
__global__ void k_permute(const int* __restrict__ eid, const int* __restrict__ csr_src,
                          const float* __restrict__ ew, const float* __restrict__ dinv,
                          float* __restrict__ csr_coef) {
    int p = blockIdx.x * blockDim.x + threadIdx.x;
    if (p >= NE) return;
    csr_coef[p] = dinv[csr_src[p]] * ew[eid[p]];
}

// ---------------- policy MLP on precomputed uv (fp16) ----------------
// per edge: h = relu(u[src] + v[dst] + b1); ew = sigmoid(h . w2 + b2)
__global__ __launch_bounds__(256) void k_policy(
    const _Float16* __restrict__ uvh, const float* __restrict__ bp1,
    const float* __restrict__ wp2, const float* __restrict__ bp2,
    const int* __restrict__ src, const int* __restrict__ dst,
    float* __restrict__ ew, float* __restrict__ deg) {
    const int lane = threadIdx.x & 63;
    const int wave = threadIdx.x >> 6;
    const int g = lane >> 3;  // 8 edge-groups of 8 lanes
    const int c = lane & 7;
    float b1v[8], w2v[8];
#pragma unroll
    for (int j = 0; j < 8; ++j) {
        b1v[j] = bp1[c * 8 + j];
        w2v[j] = wp2[c * 8 + j];
    }
    const float b2 = bp2[0];
    const int ebase = (blockIdx.x * 4 + wave) * 16;  // 16 edges per wave
#pragma unroll
    for (int it = 0; it < 2; ++it) {
        int e = ebase + it * 8 + g;
        int s = src[e], d = dst[e];
        half8 uu = *(const half8*)(uvh + (size_t)s * 128 + c * 8);
        half8 vv = *(const half8*)(uvh + (size_t)d * 128 + 64 + c * 8);
        float part = 0.f;
#pragma unroll
        for (int j = 0; j < 8; ++j) {
            float h = (float)uu[j] + (float)vv[j] + b1v[j];
            h = h > 0.f ? h : 0.f;
            part += h * w2v[j];
        }
        part += __shfl_xor(part, 1, 64);
        part += __shfl_xor(part, 2, 64);
        part += __shfl_xor(part, 4, 64);
        if (c == 0) {
            float v = 1.f / (1.f + __expf(-(part + b2)));
            ew[e] = v;
            atomicAdd(&deg[d], v);
        }
    }
}

// ---------------- uv = xb @ Wcat^T, stored fp16 ----------------
__global__ __launch_bounds__(256) void k_gemm_uv(
    const __hip_bfloat16* __restrict__ A, const __hip_bfloat16* __restrict__ Wb,
    _Float16* __restrict__ uvh) {
    const int lane = threadIdx.x & 63;
    const int wave = threadIdx.x >> 6;
    const int col = lane & 15;
    const int quad = lane >> 4;

    short8 bfrag[4][8];
    const short* wp = (const short*)Wb;
#pragma unroll
    for (int tt = 0; tt < 8; ++tt) {
        int row = tt * 16 + col;
#pragma unroll
        for (int kk = 0; kk < 4; ++kk)
            bfrag[kk][tt] = *(const short8*)(wp + row * 128 + kk * 32 + quad * 8);
    }
    int tile = blockIdx.x * 4 + wave;
    if (tile >= NN / 16) return;
    int base = tile * 16;
    const short* xs = (const short*)A;

    floatx4 acc[8];
#pragma unroll
    for (int t = 0; t < 8; ++t) acc[t] = (floatx4){0.f, 0.f, 0.f, 0.f};
#pragma unroll
    for (int kk = 0; kk < 4; ++kk) {
        short8 afrag = *(const short8*)(xs + (base + col) * 128 + kk * 32 + quad * 8);
#pragma unroll
        for (int tt = 0; tt < 8; ++tt)
            acc[tt] = __builtin_amdgcn_mfma_f32_16x16x32_bf16(afrag, bfrag[kk][tt], acc[tt], 0, 0, 0);
    }
#pragma unroll
    for (int tt = 0; tt < 8; ++tt) {
        int n = tt * 16 + col;
#pragma unroll
        for (int r = 0; r < 4; ++r) {
            int row = base + quad * 4 + r;
            uvh[(size_t)row * 128 + n] = (_Float16)acc[tt][r];
        }
    }
}

// ---------------- GCN feature transform: xl = A_in * W^T (fp16), + agg init ----------------
__global__ __launch_bounds__(256) void k_gemm(
    const __hip_bfloat16* __restrict__ A, const __hip_bfloat16* __restrict__ Wb,
    const float* __restrict__ bias, const float* __restrict__ dinv,
    _Float16* __restrict__ xlh, float* __restrict__ agg) {
    const int lane = threadIdx.x & 63;
    const int wave = threadIdx.x >> 6;
    const int col = lane & 15;
    const int quad = lane >> 4;

    short8 bfrag[4][8];
    const short* wp = (const short*)Wb;
#pragma unroll
    for (int tt = 0; tt < 8; ++tt) {
        int row = tt * 16 + col;
#pragma unroll
        for (int kk = 0; kk < 4; ++kk)
            bfrag[kk][tt] = *(const short8*)(wp + row * 128 + kk * 32 + quad * 8);
    }
    int tile = blockIdx.x * 4 + wave;
    if (tile >= NN / 16) return;  // 3125 tiles
    int base = tile * 16;
    const short* xs = (const short*)A;

    floatx4 acc[8];
#pragma unroll
    for (int t = 0; t < 8; ++t) acc[t] = (floatx4){0.f, 0.f, 0.f, 0.f};
#pragma unroll
    for (int kk = 0; kk < 4; ++kk) {
        short8 afrag = *(const short8*)(xs + (base + col) * 128 + kk * 32 + quad * 8);
#pragma unroll
        for (int tt = 0; tt < 8; ++tt)
            acc[tt] = __builtin_amdgcn_mfma_f32_16x16x32_bf16(afrag, bfrag[kk][tt], acc[tt], 0, 0, 0);
    }
    float di2[4];
#pragma unroll
    for (int r = 0; r < 4; ++r) {
        float d = dinv[base + quad * 4 + r];
        di2[r] = d * d;
    }
#pragma unroll
    for (int tt = 0; tt < 8; ++tt) {
        int n = tt * 16 + col;
        float bv = bias[n];
#pragma unroll
        for (int r = 0; r < 4; ++r) {
            int row = base + quad * 4 + r;
            float v = acc[tt][r];
            xlh[(size_t)row * 128 + n] = (_Float16)v;
            agg[(size_t)row * 128 + n] = bv + di2[r] * v;  // bias + self-loop term
        }
    }
}

// ---------------- edge aggregation: wave per node, 4 edge-groups of 16 lanes ----------------
__global__ __launch_bounds__(256) void k_scatter(
    const int* __restrict__ rowptr, const int* __restrict__ csr_src,
    const float* __restrict__ csr_coef, const float* __restrict__ dinv,
    const _Float16* __restrict__ xlh, float* __restrict__ agg) {
    int wid = (blockIdx.x * blockDim.x + threadIdx.x) >> 6;
    int lane = threadIdx.x & 63;
    if (wid >= NN) return;
    int beg = rowptr[wid], end = rowptr[wid + 1];
    int g = lane >> 4, c = lane & 15;
    float acc[8] = {0.f, 0.f, 0.f, 0.f, 0.f, 0.f, 0.f, 0.f};
    for (int p = beg + g; p < end; p += 4) {
        int s = csr_src[p];
        float coef = csr_coef[p];
        half8 v = *(const half8*)(xlh + (size_t)s * 128 + c * 8);
#pragma unroll
        for (int j = 0; j < 8; ++j) acc[j] += coef * (float)v[j];
    }
#pragma unroll
    for (int j = 0; j < 8; ++j) {
        acc[j] += __shfl_xor(acc[j], 16, 64);
        acc[j] += __shfl_xor(acc[j], 32, 64);
    }
    if (g == 0) {
        float dn = dinv[wid];
        float4* ap = (float4*)(agg + (size_t)wid * 128 + c * 8);
        float4 a0 = ap[0], a1 = ap[1];
        a0.x += dn * acc[0]; a0.y += dn * acc[1]; a0.z += dn * acc[2]; a0.w += dn * acc[3];
        a1.x += dn * acc[4]; a1.y += dn * acc[5]; a1.z += dn * acc[6]; a1.w += dn * acc[7];
        ap[0] = a0; ap[1] = a1;
    }
}

// ---------------- output head: sigmoid(relu(agg) @ Wlin^T + blin) ----------------
__global__ __launch_bounds__(256) void k_out(const float* __restrict__ agg,
                                             const float* __restrict__ wlin,
                                             const float* __restrict__ blin,
                                             float* __restrict__ out) {
    int wid = (blockIdx.x * blockDim.x + threadIdx.x) >> 6;
    int lane = threadIdx.x & 63;
    if (wid >= NN) return;
    float v0 = agg[(size_t)wid * 128 + lane];
    float v1 = agg[(size_t)wid * 128 + 64 + lane];
    v0 = v0 > 0.f ? v0 : 0.f;
    v1 = v1 > 0.f ? v1 : 0.f;
    float p0 = v0 * wlin[lane] + v1 * wlin[64 + lane];
    float p1 = v0 * wlin[128 + lane] + v1 * wlin[192 + lane];
#pragma unroll
    for (int off = 1; off < 64; off <<= 1) {
        p0 += __shfl_xor(p0, off, 64);
        p1 += __shfl_xor(p1, off, 64);
    }
    if (lane == 0) {
        out[wid * 2 + 0] = 1.f / (1.f + __expf(-(p0 + blin[0])));
        out[wid * 2 + 1] = 1.f / (1.f + __expf(-(p1 + blin[1])));
    }
}

// ---------------- host launcher ----------------

extern "C" void kernel_launch(void* const* d_in, const int* in_sizes, int n_in,
                              void* d_out, int out_size, void* d_ws, size_t ws_size,
                              hipStream_t stream) {
    const float* x = (const float*)d_in[0];
    const int* eidx_raw = (const int*)d_in[1];
    const float* W_p1 = (const float*)d_in[2];
    const float* b_p1 = (const float*)d_in[3];
    const float* W_p2 = (const float*)d_in[4];
    const float* b_p2 = (const float*)d_in[5];
    const float* W1 = (const float*)d_in[6];
    const float* b1 = (const float*)d_in[7];
    const float* W2 = (const float*)d_in[8];
    const float* b2 = (const float*)d_in[9];
    const float* W_lin = (const float*)d_in[10];
    const float* b_lin = (const float*)d_in[11];
    float* out = (float*)d_out;

    char* ws = (char*)d_ws;
    size_t off = 0;
    auto alloc = [&](size_t bytes) -> void* {
        off = (off + 255) & ~(size_t)255;
        void* p = ws + off;
        off += bytes;
        return p;
    };
    float* ew = (float*)alloc(NE * 4);
    float* deg = (float*)alloc(NN * 4);  // becomes dinv in place
    int* rowptr = (int*)alloc((NN + 1) * 4);
    int* cursor = (int*)alloc(NN * 4);
    int* count = (int*)alloc(NN * 4);
    int* flag = (int*)alloc(4);
    int* eid = (int*)alloc(NE * 4);  // also reused as scan tmp before fill
    int* bsums = (int*)alloc(128 * 4);
    int* src32 = (int*)alloc(NE * 4);
    int* dst32 = (int*)alloc(NE * 4);
    int* csr_src = (int*)alloc(NE * 4);
    float* csr_coef = (float*)alloc(NE * 4);
    __hip_bfloat16* xb = (__hip_bfloat16*)alloc((size_t)NN * 128 * 2);
    _Float16* xlh = (_Float16*)alloc((size_t)NN * 128 * 2);
    _Float16* uvh = (_Float16*)alloc((size_t)NN * 128 * 2);
    float* agg = (float*)alloc((size_t)NN * 128 * 4);
    __hip_bfloat16* wcatb = (__hip_bfloat16*)alloc(128 * 128 * 2);
    __hip_bfloat16* w1b = (__hip_bfloat16*)alloc(128 * 128 * 2);
    __hip_bfloat16* w2b = (__hip_bfloat16*)alloc(128 * 128 * 2);
    int* tmp = eid;

    const int TB = 256;
    int gN = (NN + TB - 1) / TB;
    int gE = (NE + TB - 1) / TB;

    k_zero_init<<<gN, TB, 0, stream>>>(count, flag);
    k_detect<<<1, 256, 0, stream>>>(eidx_raw, flag);
    k_extract<<<gE, TB, 0, stream>>>(eidx_raw, flag, src32, dst32, count);

    k_cvt_bf16<<<(NN * 128 + TB - 1) / TB, TB, 0, stream>>>(x, xb, NN * 128, 0);
    k_cvt_wcat<<<(128 * 128 + TB - 1) / TB, TB, 0, stream>>>(W_p1, wcatb);
    k_cvt_bf16<<<(128 * 128 + TB - 1) / TB, TB, 0, stream>>>(W1, w1b, 128 * 128, 0);
    k_cvt_bf16<<<(128 * 128 + TB - 1) / TB, TB, 0, stream>>>(W2, w2b, 128 * 128, 0);

    // uv = xb @ Wcat^T (fp16)
    k_gemm_uv<<<(NN / 16 + 3) / 4, TB, 0, stream>>>(xb, wcatb, uvh);

    k_scan_block<<<98, 512, 0, stream>>>(count, tmp, bsums);
    k_scan_sums<<<1, 128, 0, stream>>>(bsums, 98);
    k_finalize_scan<<<gN, TB, 0, stream>>>(tmp, count, bsums, rowptr, cursor, deg);

    k_policy<<<NE / 16 / 4, TB, 0, stream>>>(uvh, b_p1, W_p2, b_p2, src32, dst32, ew, deg);
    k_fill<<<gE, TB, 0, stream>>>(dst32, src32, cursor, eid, csr_src);
    k_dinv<<<gN, TB, 0, stream>>>(deg);
    k_permute<<<gE, TB, 0, stream>>>(eid, csr_src, ew, deg, csr_coef);

    // layer 1
    k_gemm<<<(NN / 16 + 3) / 4, TB, 0, stream>>>(xb, w1b, b1, deg, xlh, agg);
    k_scatter<<<(NN + 3) / 4, TB, 0, stream>>>(rowptr, csr_src, csr_coef, deg, xlh, agg);
    // layer 2 (input = relu(agg1) as bf16, reuse xb)
    k_cvt_bf16<<<(NN * 128 + TB - 1) / TB, TB, 0, stream>>>(agg, xb, NN * 128, 1);
    k_gemm<<<(NN / 16 + 3) / 4, TB, 0, stream>>>(xb, w2b, b2, deg, xlh, agg);
    k_scatter<<<(NN + 3) / 4, TB, 0, stream>>>(rowptr, csr_src, csr_coef, deg, xlh, agg);

    k_out<<<(NN + 3) / 4, TB, 0, stream>>>(agg, W_lin, b_lin, out);
}

// Round 3
// 333.269 us; speedup vs baseline: 1.8125x; 1.1302x over previous
//
#include <hip/hip_runtime.h>
#include <hip/hip_bf16.h>

#define NN 50000
#define NE 600000
// dims: in=128, hid=128, policy hidden=64, out=2

typedef __attribute__((ext_vector_type(8))) short short8;     // 8 bf16 (4 VGPRs)
typedef __attribute__((ext_vector_type(8))) _Float16 half8;   // 8 fp16
typedef __attribute__((ext_vector_type(4))) float floatx4;    // 4 f32 acc

__device__ __forceinline__ short bf16_bits(float v) {
    __hip_bfloat16 h = __float2bfloat16(v);
    return *reinterpret_cast<short*>(&h);
}

// ---------------- init: zero count + detect edge_index layout ----------------
__global__ void k_init(const int* __restrict__ raw, int* __restrict__ count,
                       int* __restrict__ flag) {
    int i = blockIdx.x * blockDim.x + threadIdx.x;
    if (i < NN) count[i] = 0;
    if (blockIdx.x == 0) {
        if (threadIdx.x == 0) *flag = 0;
        __syncthreads();
        int any = 0;
        for (int j = threadIdx.x; j < 1024; j += 256) any |= raw[2 * j + 1];
        if (any) atomicOr(flag, 1);  // flag=1 -> int32 layout
    }
}

// extract src/dst (either layout) + fused degree count
__global__ void k_extract(const int* __restrict__ raw, const int* __restrict__ flag,
                          int* __restrict__ src32, int* __restrict__ dst32,
                          int* __restrict__ count) {
    int e = blockIdx.x * blockDim.x + threadIdx.x;
    if (e >= NE) return;
    int s, d;
    if (*flag) {
        s = raw[e];
        d = raw[NE + e];
    } else {
        const long long* r64 = (const long long*)raw;
        s = (int)r64[e];
        d = (int)r64[NE + e];
    }
    src32[e] = s;
    dst32[e] = d;
    atomicAdd(&count[d], 1);
}

// all three weight matrices -> bf16 (wcat is the split-cat permutation of W_p1)
__global__ void k_cvt_w(const float* __restrict__ wp1, const float* __restrict__ w1,
                        const float* __restrict__ w2, __hip_bfloat16* __restrict__ wcatb,
                        __hip_bfloat16* __restrict__ w1b, __hip_bfloat16* __restrict__ w2b) {
    int i = blockIdx.x * blockDim.x + threadIdx.x;
    if (i < 16384) {
        int r = i >> 7, c = i & 127;
        float v = (r < 64) ? wp1[r * 256 + c] : wp1[(r - 64) * 256 + 128 + c];
        wcatb[i] = __float2bfloat16(v);
    } else if (i < 32768) {
        w1b[i - 16384] = __float2bfloat16(w1[i - 16384]);
    } else if (i < 49152) {
        w2b[i - 32768] = __float2bfloat16(w2[i - 32768]);
    }
}

// two-level inclusive scan of count[NN]
__global__ void k_scan_block(const int* __restrict__ count, int* __restrict__ tmp,
                             int* __restrict__ bsums) {
    __shared__ int s[512];
    int tid = threadIdx.x;
    int i = blockIdx.x * 512 + tid;
    s[tid] = (i < NN) ? count[i] : 0;
    __syncthreads();
    for (int off = 1; off < 512; off <<= 1) {
        int t = (tid >= off) ? s[tid - off] : 0;
        __syncthreads();
        s[tid] += t;
        __syncthreads();
    }
    if (i < NN) tmp[i] = s[tid];
    if (tid == 511) bsums[blockIdx.x] = s[511];
}

__global__ void k_scan_sums(int* __restrict__ bsums, int nb) {
    __shared__ int s[128];
    int tid = threadIdx.x;
    int v = (tid < nb) ? bsums[tid] : 0;
    s[tid] = v;
    __syncthreads();
    for (int off = 1; off < 128; off <<= 1) {
        int t = (tid >= off) ? s[tid - off] : 0;
        __syncthreads();
        s[tid] += t;
        __syncthreads();
    }
    if (tid < nb) bsums[tid] = s[tid] - v;  // exclusive
}

__global__ void k_finalize_scan(const int* __restrict__ tmp, const int* __restrict__ count,
                                const int* __restrict__ bsums, int* __restrict__ rowptr,
                                int* __restrict__ cursor, float* __restrict__ deg) {
    int i = blockIdx.x * blockDim.x + threadIdx.x;
    if (i >= NN) return;
    int incl = tmp[i] + bsums[i >> 9];
    rowptr[i + 1] = incl;
    cursor[i] = incl - count[i];
    deg[i] = 1.0f;  // self-loop weight
    if (i == 0) rowptr[0] = 0;
}

// CSR fill with fused coef: meta[pos] = {src, dinv[src]*ew[e]}
__global__ void k_fill(const int* __restrict__ dst, const int* __restrict__ src,
                       const float* __restrict__ ew, const float* __restrict__ deg,
                       int* __restrict__ cursor, int2* __restrict__ meta) {
    int e = blockIdx.x * blockDim.x + threadIdx.x;
    if (e >= NE) return;
    int s = src[e];
    int pos = atomicAdd(&cursor[dst[e]], 1);
    float coef = rsqrtf(deg[s]) * ew[e];
    meta[pos] = make_int2(s, __float_as_int(coef));
}

// ---------------- uv = x @ Wcat^T (fp16, b_p1 folded into v half); also emits xb ----------------
__global__ __launch_bounds__(256) void k_gemm_uv(
    const float* __restrict__ x, const __hip_bfloat16* __restrict__ Wb,
    const float* __restrict__ bp1, _Float16* __restrict__ uvh,
    __hip_bfloat16* __restrict__ xb) {
    const int lane = threadIdx.x & 63;
    const int wave = threadIdx.x >> 6;
    const int col = lane & 15;
    const int quad = lane >> 4;

    short8 bfrag[4][8];
    const short* wp = (const short*)Wb;
#pragma unroll
    for (int tt = 0; tt < 8; ++tt) {
        int row = tt * 16 + col;
#pragma unroll
        for (int kk = 0; kk < 4; ++kk)
            bfrag[kk][tt] = *(const short8*)(wp + row * 128 + kk * 32 + quad * 8);
    }
    int tile = blockIdx.x * 4 + wave;
    if (tile >= NN / 16) return;
    int base = tile * 16;

    floatx4 acc[8];
#pragma unroll
    for (int t = 0; t < 8; ++t) acc[t] = (floatx4){0.f, 0.f, 0.f, 0.f};
#pragma unroll
    for (int kk = 0; kk < 4; ++kk) {
        const float* xrow = x + (size_t)(base + col) * 128 + kk * 32 + quad * 8;
        float4 f0 = ((const float4*)xrow)[0];
        float4 f1 = ((const float4*)xrow)[1];
        short8 afrag;
        afrag[0] = bf16_bits(f0.x); afrag[1] = bf16_bits(f0.y);
        afrag[2] = bf16_bits(f0.z); afrag[3] = bf16_bits(f0.w);
        afrag[4] = bf16_bits(f1.x); afrag[5] = bf16_bits(f1.y);
        afrag[6] = bf16_bits(f1.z); afrag[7] = bf16_bits(f1.w);
        *(short8*)((short*)xb + (size_t)(base + col) * 128 + kk * 32 + quad * 8) = afrag;
#pragma unroll
        for (int tt = 0; tt < 8; ++tt)
            acc[tt] = __builtin_amdgcn_mfma_f32_16x16x32_bf16(afrag, bfrag[kk][tt], acc[tt], 0, 0, 0);
    }
#pragma unroll
    for (int tt = 0; tt < 8; ++tt) {
        int n = tt * 16 + col;
        float badd = (tt >= 4) ? bp1[n - 64] : 0.f;
#pragma unroll
        for (int r = 0; r < 4; ++r) {
            int row = base + quad * 4 + r;
            uvh[(size_t)row * 128 + n] = (_Float16)(acc[tt][r] + badd);
        }
    }
}

// ---------------- policy MLP: one lane per edge ----------------
// h = relu(u[src] + v'[dst]); ew = sigmoid(h . w2 + b2);  v' has b1 folded in
__global__ __launch_bounds__(256) void k_policy(
    const _Float16* __restrict__ uvh, const float* __restrict__ wp2,
    const float* __restrict__ bp2, const int* __restrict__ src,
    const int* __restrict__ dst, float* __restrict__ ew, float* __restrict__ deg) {
    int e = blockIdx.x * blockDim.x + threadIdx.x;
    if (e >= NE) return;
    int s = src[e], d = dst[e];
    const half8* up = (const half8*)(uvh + (size_t)s * 128);
    const half8* vp = (const half8*)(uvh + (size_t)d * 128 + 64);
    float part = 0.f;
#pragma unroll
    for (int half = 0; half < 2; ++half) {
        half8 u0 = up[half * 4 + 0], u1 = up[half * 4 + 1];
        half8 u2 = up[half * 4 + 2], u3 = up[half * 4 + 3];
        half8 v0 = vp[half * 4 + 0], v1 = vp[half * 4 + 1];
        half8 v2 = vp[half * 4 + 2], v3 = vp[half * 4 + 3];
#pragma unroll
        for (int k = 0; k < 8; ++k) {
            int base = half * 32;
            float h0 = (float)u0[k] + (float)v0[k];
            float h1 = (float)u1[k] + (float)v1[k];
            float h2 = (float)u2[k] + (float)v2[k];
            float h3 = (float)u3[k] + (float)v3[k];
            h0 = h0 > 0.f ? h0 : 0.f;
            h1 = h1 > 0.f ? h1 : 0.f;
            h2 = h2 > 0.f ? h2 : 0.f;
            h3 = h3 > 0.f ? h3 : 0.f;
            part += h0 * wp2[base + k] + h1 * wp2[base + 8 + k] +
                    h2 * wp2[base + 16 + k] + h3 * wp2[base + 24 + k];
        }
    }
    float v = 1.f / (1.f + __expf(-(part + bp2[0])));
    ew[e] = v;
    atomicAdd(&deg[d], v);
}

// ---------------- GCN feature transform: xl = A_in * W^T (fp16), + agg init ----------------
__global__ __launch_bounds__(256) void k_gemm(
    const __hip_bfloat16* __restrict__ A, const __hip_bfloat16* __restrict__ Wb,
    const float* __restrict__ bias, const float* __restrict__ deg,
    _Float16* __restrict__ xlh, float* __restrict__ agg) {
    const int lane = threadIdx.x & 63;
    const int wave = threadIdx.x >> 6;
    const int col = lane & 15;
    const int quad = lane >> 4;

    short8 bfrag[4][8];
    const short* wp = (const short*)Wb;
#pragma unroll
    for (int tt = 0; tt < 8; ++tt) {
        int row = tt * 16 + col;
#pragma unroll
        for (int kk = 0; kk < 4; ++kk)
            bfrag[kk][tt] = *(const short8*)(wp + row * 128 + kk * 32 + quad * 8);
    }
    int tile = blockIdx.x * 4 + wave;
    if (tile >= NN / 16) return;  // 3125 tiles
    int base = tile * 16;
    const short* xs = (const short*)A;

    floatx4 acc[8];
#pragma unroll
    for (int t = 0; t < 8; ++t) acc[t] = (floatx4){0.f, 0.f, 0.f, 0.f};
#pragma unroll
    for (int kk = 0; kk < 4; ++kk) {
        short8 afrag = *(const short8*)(xs + (size_t)(base + col) * 128 + kk * 32 + quad * 8);
#pragma unroll
        for (int tt = 0; tt < 8; ++tt)
            acc[tt] = __builtin_amdgcn_mfma_f32_16x16x32_bf16(afrag, bfrag[kk][tt], acc[tt], 0, 0, 0);
    }
    float di2[4];
#pragma unroll
    for (int r = 0; r < 4; ++r) di2[r] = 1.0f / deg[base + quad * 4 + r];  // dinv^2
#pragma unroll
    for (int tt = 0; tt < 8; ++tt) {
        int n = tt * 16 + col;
        float bv = bias[n];
#pragma unroll
        for (int r = 0; r < 4; ++r) {
            int row = base + quad * 4 + r;
            float v = acc[tt][r];
            xlh[(size_t)row * 128 + n] = (_Float16)v;
            agg[(size_t)row * 128 + n] = bv + di2[r] * v;  // bias + self-loop term
        }
    }
}

// ---------------- scatter core: wave per node, 4 edge-groups of 16 lanes ----------------
__device__ __forceinline__ void scatter_core(
    const int* __restrict__ rowptr, const int2* __restrict__ meta,
    const _Float16* __restrict__ xlh, int wid, int g, int c, float acc[8]) {
    int beg = rowptr[wid], end = rowptr[wid + 1];
    int p = beg + g;
    for (; p + 4 < end; p += 8) {
        int2 m1 = meta[p];
        int2 m2 = meta[p + 4];
        half8 r1 = *(const half8*)(xlh + (size_t)m1.x * 128 + c * 8);
        half8 r2 = *(const half8*)(xlh + (size_t)m2.x * 128 + c * 8);
        float c1 = __int_as_float(m1.y), c2 = __int_as_float(m2.y);
#pragma unroll
        for (int j = 0; j < 8; ++j) acc[j] += c1 * (float)r1[j] + c2 * (float)r2[j];
    }
    if (p < end) {
        int2 m1 = meta[p];
        half8 r1 = *(const half8*)(xlh + (size_t)m1.x * 128 + c * 8);
        float c1 = __int_as_float(m1.y);
#pragma unroll
        for (int j = 0; j < 8; ++j) acc[j] += c1 * (float)r1[j];
    }
#pragma unroll
    for (int j = 0; j < 8; ++j) {
        acc[j] += __shfl_xor(acc[j], 16, 64);
        acc[j] += __shfl_xor(acc[j], 32, 64);
    }
}

// mid-layer scatter: emits relu(agg) as bf16 input for layer 2
__global__ __launch_bounds__(256) void k_scatter_mid(
    const int* __restrict__ rowptr, const int2* __restrict__ meta,
    const float* __restrict__ deg, const _Float16* __restrict__ xlh,
    const float* __restrict__ agg, __hip_bfloat16* __restrict__ xb2) {
    int wid = (blockIdx.x * blockDim.x + threadIdx.x) >> 6;
    int lane = threadIdx.x & 63;
    if (wid >= NN) return;
    int g = lane >> 4, c = lane & 15;
    float acc[8] = {0.f, 0.f, 0.f, 0.f, 0.f, 0.f, 0.f, 0.f};
    scatter_core(rowptr, meta, xlh, wid, g, c, acc);
    if (g == 0) {
        float dn = rsqrtf(deg[wid]);
        const float4* ap = (const float4*)(agg + (size_t)wid * 128 + c * 8);
        float4 a0 = ap[0], a1 = ap[1];
        float v[8] = {a0.x, a0.y, a0.z, a0.w, a1.x, a1.y, a1.z, a1.w};
        short8 o;
#pragma unroll
        for (int j = 0; j < 8; ++j) {
            float t = v[j] + dn * acc[j];
            t = t > 0.f ? t : 0.f;
            o[j] = bf16_bits(t);
        }
        *(short8*)((short*)xb2 + (size_t)wid * 128 + c * 8) = o;
    }
}

// final scatter fused with output head: sigmoid(relu(agg) @ Wlin^T + blin)
__global__ __launch_bounds__(256) void k_scatter_out(
    const int* __restrict__ rowptr, const int2* __restrict__ meta,
    const float* __restrict__ deg, const _Float16* __restrict__ xlh,
    const float* __restrict__ agg, const float* __restrict__ wlin,
    const float* __restrict__ blin, float* __restrict__ out) {
    int wid = (blockIdx.x * blockDim.x + threadIdx.x) >> 6;
    int lane = threadIdx.x & 63;
    if (wid >= NN) return;
    int g = lane >> 4, c = lane & 15;
    float acc[8] = {0.f, 0.f, 0.f, 0.f, 0.f, 0.f, 0.f, 0.f};
    scatter_core(rowptr, meta, xlh, wid, g, c, acc);
    if (g == 0) {
        float dn = rsqrtf(deg[wid]);
        const float4* ap = (const float4*)(agg + (size_t)wid * 128 + c * 8);
        float4 a0 = ap[0], a1 = ap[1];
        float v[8] = {a0.x, a0.y, a0.z, a0.w, a1.x, a1.y, a1.z, a1.w};
        float p0 = 0.f, p1 = 0.f;
#pragma unroll
        for (int j = 0; j < 8; ++j) {
            float t = v[j] + dn * acc[j];
            t = t > 0.f ? t : 0.f;
            p0 += t * wlin[c * 8 + j];
            p1 += t * wlin[128 + c * 8 + j];
        }
#pragma unroll
        for (int off = 1; off < 16; off <<= 1) {
            p0 += __shfl_xor(p0, off, 64);
            p1 += __shfl_xor(p1, off, 64);
        }
        if (c == 0) {
            out[wid * 2 + 0] = 1.f / (1.f + __expf(-(p0 + blin[0])));
            out[wid * 2 + 1] = 1.f / (1.f + __expf(-(p1 + blin[1])));
        }
    }
}

// ---------------- host launcher ----------------

extern "C" void kernel_launch(void* const* d_in, const int* in_sizes, int n_in,
                              void* d_out, int out_size, void* d_ws, size_t ws_size,
                              hipStream_t stream) {
    const float* x = (const float*)d_in[0];
    const int* eidx_raw = (const int*)d_in[1];
    const float* W_p1 = (const float*)d_in[2];
    const float* b_p1 = (const float*)d_in[3];
    const float* W_p2 = (const float*)d_in[4];
    const float* b_p2 = (const float*)d_in[5];
    const float* W1 = (const float*)d_in[6];
    const float* b1 = (const float*)d_in[7];
    const float* W2 = (const float*)d_in[8];
    const float* b2 = (const float*)d_in[9];
    const float* W_lin = (const float*)d_in[10];
    const float* b_lin = (const float*)d_in[11];
    float* out = (float*)d_out;

    char* ws = (char*)d_ws;
    size_t off = 0;
    auto alloc = [&](size_t bytes) -> void* {
        off = (off + 255) & ~(size_t)255;
        void* p = ws + off;
        off += bytes;
        return p;
    };
    float* ew = (float*)alloc(NE * 4);
    float* deg = (float*)alloc(NN * 4);
    int* rowptr = (int*)alloc((NN + 1) * 4);
    int* cursor = (int*)alloc(NN * 4);
    int* count = (int*)alloc(NN * 4);
    int* flag = (int*)alloc(4);
    int* bsums = (int*)alloc(128 * 4);
    int* src32 = (int*)alloc(NE * 4);
    int* dst32 = (int*)alloc(NE * 4);
    int2* meta = (int2*)alloc((size_t)NE * 8);  // reused as scan tmp before fill
    __hip_bfloat16* xb = (__hip_bfloat16*)alloc((size_t)NN * 128 * 2);  // reused as xb2
    _Float16* xlh = (_Float16*)alloc((size_t)NN * 128 * 2);
    _Float16* uvh = (_Float16*)alloc((size_t)NN * 128 * 2);
    float* agg = (float*)alloc((size_t)NN * 128 * 4);
    __hip_bfloat16* wcatb = (__hip_bfloat16*)alloc(128 * 128 * 2);
    __hip_bfloat16* w1b = (__hip_bfloat16*)alloc(128 * 128 * 2);
    __hip_bfloat16* w2b = (__hip_bfloat16*)alloc(128 * 128 * 2);
    int* tmp = (int*)meta;

    const int TB = 256;
    int gN = (NN + TB - 1) / TB;
    int gE = (NE + TB - 1) / TB;
    int gG = (NN / 16 + 3) / 4;
    int gS = (NN + 3) / 4;

    k_init<<<gN, TB, 0, stream>>>(eidx_raw, count, flag);
    k_extract<<<gE, TB, 0, stream>>>(eidx_raw, flag, src32, dst32, count);
    k_cvt_w<<<192, TB, 0, stream>>>(W_p1, W1, W2, wcatb, w1b, w2b);

    // uv = x @ Wcat^T (fp16, b1 folded into v); also emits xb (bf16 of x)
    k_gemm_uv<<<gG, TB, 0, stream>>>(x, wcatb, b_p1, uvh, xb);

    k_scan_block<<<98, 512, 0, stream>>>(count, tmp, bsums);
    k_scan_sums<<<1, 128, 0, stream>>>(bsums, 98);
    k_finalize_scan<<<gN, TB, 0, stream>>>(tmp, count, bsums, rowptr, cursor, deg);

    k_policy<<<gE, TB, 0, stream>>>(uvh, W_p2, b_p2, src32, dst32, ew, deg);
    k_fill<<<gE, TB, 0, stream>>>(dst32, src32, ew, deg, cursor, meta);

    // layer 1
    k_gemm<<<gG, TB, 0, stream>>>(xb, w1b, b1, deg, xlh, agg);
    k_scatter_mid<<<gS, TB, 0, stream>>>(rowptr, meta, deg, xlh, agg, xb);
    // layer 2
    k_gemm<<<gG, TB, 0, stream>>>(xb, w2b, b2, deg, xlh, agg);
    k_scatter_out<<<gS, TB, 0, stream>>>(rowptr, meta, deg, xlh, agg, W_lin, b_lin, out);
}

// Round 4
// 317.625 us; speedup vs baseline: 1.9018x; 1.0493x over previous
//
#include <hip/hip_runtime.h>
#include <hip/hip_bf16.h>

#define NN 50000
#define NE 600000
// dims: in=128, hid=128, policy hidden=64, out=2

typedef __attribute__((ext_vector_type(8))) short short8;     // 8 bf16 (4 VGPRs)
typedef __attribute__((ext_vector_type(8))) _Float16 half8;   // 8 fp16
typedef __attribute__((ext_vector_type(4))) float floatx4;    // 4 f32 acc

__device__ __forceinline__ short bf16_bits(float v) {
    __hip_bfloat16 h = __float2bfloat16(v);
    return *reinterpret_cast<short*>(&h);
}

// ---------------- init: zero count + detect edge_index layout ----------------
__global__ void k_init(const int* __restrict__ raw, int* __restrict__ count,
                       int* __restrict__ flag) {
    int i = blockIdx.x * blockDim.x + threadIdx.x;
    if (i < NN) count[i] = 0;
    if (blockIdx.x == 0) {
        if (threadIdx.x == 0) *flag = 0;
        __syncthreads();
        int any = 0;
        for (int j = threadIdx.x; j < 1024; j += 256) any |= raw[2 * j + 1];
        if (any) atomicOr(flag, 1);  // flag=1 -> int32 layout
    }
}

// degree count straight off the raw edge list
__global__ void k_count(const int* __restrict__ raw, const int* __restrict__ flag,
                        int* __restrict__ count) {
    int e = blockIdx.x * blockDim.x + threadIdx.x;
    if (e >= NE) return;
    int d = (*flag) ? raw[NE + e] : (int)((const long long*)raw)[NE + e];
    atomicAdd(&count[d], 1);
}

// all three weight matrices -> bf16 (wcat is the split-cat permutation of W_p1)
__global__ void k_cvt_w(const float* __restrict__ wp1, const float* __restrict__ w1,
                        const float* __restrict__ w2, __hip_bfloat16* __restrict__ wcatb,
                        __hip_bfloat16* __restrict__ w1b, __hip_bfloat16* __restrict__ w2b) {
    int i = blockIdx.x * blockDim.x + threadIdx.x;
    if (i < 16384) {
        int r = i >> 7, c = i & 127;
        float v = (r < 64) ? wp1[r * 256 + c] : wp1[(r - 64) * 256 + 128 + c];
        wcatb[i] = __float2bfloat16(v);
    } else if (i < 32768) {
        w1b[i - 16384] = __float2bfloat16(w1[i - 16384]);
    } else if (i < 49152) {
        w2b[i - 32768] = __float2bfloat16(w2[i - 32768]);
    }
}

// two-level inclusive scan of count[NN]
__global__ void k_scan_block(const int* __restrict__ count, int* __restrict__ tmp,
                             int* __restrict__ bsums) {
    __shared__ int s[512];
    int tid = threadIdx.x;
    int i = blockIdx.x * 512 + tid;
    s[tid] = (i < NN) ? count[i] : 0;
    __syncthreads();
    for (int off = 1; off < 512; off <<= 1) {
        int t = (tid >= off) ? s[tid - off] : 0;
        __syncthreads();
        s[tid] += t;
        __syncthreads();
    }
    if (i < NN) tmp[i] = s[tid];
    if (tid == 511) bsums[blockIdx.x] = s[511];
}

__global__ void k_scan_sums(int* __restrict__ bsums, int nb) {
    __shared__ int s[128];
    int tid = threadIdx.x;
    int v = (tid < nb) ? bsums[tid] : 0;
    s[tid] = v;
    __syncthreads();
    for (int off = 1; off < 128; off <<= 1) {
        int t = (tid >= off) ? s[tid - off] : 0;
        __syncthreads();
        s[tid] += t;
        __syncthreads();
    }
    if (tid < nb) bsums[tid] = s[tid] - v;  // exclusive
}

__global__ void k_finalize_scan(const int* __restrict__ tmp, const int* __restrict__ count,
                                const int* __restrict__ bsums, int* __restrict__ rowptr,
                                int* __restrict__ cursor) {
    int i = blockIdx.x * blockDim.x + threadIdx.x;
    if (i >= NN) return;
    int incl = tmp[i] + bsums[i >> 9];
    rowptr[i + 1] = incl;
    cursor[i] = incl - count[i];
    if (i == 0) rowptr[0] = 0;
}

// CSR fill from raw edges: meta[pos] = {src, 0}
__global__ void k_fill(const int* __restrict__ raw, const int* __restrict__ flag,
                       int* __restrict__ cursor, int2* __restrict__ meta) {
    int e = blockIdx.x * blockDim.x + threadIdx.x;
    if (e >= NE) return;
    int s, d;
    if (*flag) {
        s = raw[e];
        d = raw[NE + e];
    } else {
        const long long* r64 = (const long long*)raw;
        s = (int)r64[e];
        d = (int)r64[NE + e];
    }
    int pos = atomicAdd(&cursor[d], 1);
    meta[pos] = make_int2(s, 0);
}

// ---------------- uv = x @ Wcat^T (fp16, b_p1 folded into v half); also emits xb ----------------
__global__ __launch_bounds__(256) void k_gemm_uv(
    const float* __restrict__ x, const __hip_bfloat16* __restrict__ Wb,
    const float* __restrict__ bp1, _Float16* __restrict__ uvh,
    __hip_bfloat16* __restrict__ xb) {
    const int lane = threadIdx.x & 63;
    const int wave = threadIdx.x >> 6;
    const int col = lane & 15;
    const int quad = lane >> 4;

    short8 bfrag[4][8];
    const short* wp = (const short*)Wb;
#pragma unroll
    for (int tt = 0; tt < 8; ++tt) {
        int row = tt * 16 + col;
#pragma unroll
        for (int kk = 0; kk < 4; ++kk)
            bfrag[kk][tt] = *(const short8*)(wp + row * 128 + kk * 32 + quad * 8);
    }
    int tile = blockIdx.x * 4 + wave;
    if (tile >= NN / 16) return;
    int base = tile * 16;

    floatx4 acc[8];
#pragma unroll
    for (int t = 0; t < 8; ++t) acc[t] = (floatx4){0.f, 0.f, 0.f, 0.f};
#pragma unroll
    for (int kk = 0; kk < 4; ++kk) {
        const float* xrow = x + (size_t)(base + col) * 128 + kk * 32 + quad * 8;
        float4 f0 = ((const float4*)xrow)[0];
        float4 f1 = ((const float4*)xrow)[1];
        short8 afrag;
        afrag[0] = bf16_bits(f0.x); afrag[1] = bf16_bits(f0.y);
        afrag[2] = bf16_bits(f0.z); afrag[3] = bf16_bits(f0.w);
        afrag[4] = bf16_bits(f1.x); afrag[5] = bf16_bits(f1.y);
        afrag[6] = bf16_bits(f1.z); afrag[7] = bf16_bits(f1.w);
        *(short8*)((short*)xb + (size_t)(base + col) * 128 + kk * 32 + quad * 8) = afrag;
#pragma unroll
        for (int tt = 0; tt < 8; ++tt)
            acc[tt] = __builtin_amdgcn_mfma_f32_16x16x32_bf16(afrag, bfrag[kk][tt], acc[tt], 0, 0, 0);
    }
#pragma unroll
    for (int tt = 0; tt < 8; ++tt) {
        int n = tt * 16 + col;
        float badd = (tt >= 4) ? bp1[n - 64] : 0.f;
#pragma unroll
        for (int r = 0; r < 4; ++r) {
            int row = base + quad * 4 + r;
            uvh[(size_t)row * 128 + n] = (_Float16)(acc[tt][r] + badd);
        }
    }
}

// ---------------- policy MLP in CSR order: wave per dst node ----------------
// v[dst] loaded once per node; per in-edge gather u[src]; ew -> meta.y; deg w/o atomics
__global__ __launch_bounds__(256) void k_policy_csr(
    const _Float16* __restrict__ uvh, const float* __restrict__ wp2,
    const float* __restrict__ bp2, const int* __restrict__ rowptr,
    int2* __restrict__ meta, float* __restrict__ deg) {
    int wid = (blockIdx.x * blockDim.x + threadIdx.x) >> 6;
    int lane = threadIdx.x & 63;
    if (wid >= NN) return;
    int g = lane >> 3, c = lane & 7;  // 8 edge-groups of 8 lanes
    half8 vh = *(const half8*)(uvh + (size_t)wid * 128 + 64 + c * 8);
    float vv[8], w2v[8];
    const float4* w2p = (const float4*)(wp2 + c * 8);
    float4 wa = w2p[0], wb = w2p[1];
    w2v[0] = wa.x; w2v[1] = wa.y; w2v[2] = wa.z; w2v[3] = wa.w;
    w2v[4] = wb.x; w2v[5] = wb.y; w2v[6] = wb.z; w2v[7] = wb.w;
#pragma unroll
    for (int j = 0; j < 8; ++j) vv[j] = (float)vh[j];
    float b2 = bp2[0];
    int beg = rowptr[wid], end = rowptr[wid + 1];
    float degsum = 0.f;
    for (int p = beg + g; p < end; p += 8) {
        int s = meta[p].x;
        half8 uh = *(const half8*)(uvh + (size_t)s * 128 + c * 8);
        float part = 0.f;
#pragma unroll
        for (int j = 0; j < 8; ++j) {
            float h = (float)uh[j] + vv[j];
            h = h > 0.f ? h : 0.f;
            part += h * w2v[j];
        }
        part += __shfl_xor(part, 1, 64);
        part += __shfl_xor(part, 2, 64);
        part += __shfl_xor(part, 4, 64);
        if (c == 0) {
            float vew = 1.f / (1.f + __expf(-(part + b2)));
            meta[p].y = __float_as_int(vew);
            degsum += vew;
        }
    }
    degsum += __shfl_xor(degsum, 8, 64);
    degsum += __shfl_xor(degsum, 16, 64);
    degsum += __shfl_xor(degsum, 32, 64);
    if (lane == 0) deg[wid] = 1.f + degsum;
}

// fold dinv[src] into per-edge coef: meta.y = rsqrt(deg[src]) * ew
__global__ void k_coef(int2* __restrict__ meta, const float* __restrict__ deg) {
    int p = blockIdx.x * blockDim.x + threadIdx.x;
    if (p >= NE) return;
    int2 m = meta[p];
    meta[p].y = __float_as_int(rsqrtf(deg[m.x]) * __int_as_float(m.y));
}

// ---------------- GCN feature transform: xl = A_in * W^T (fp16) ----------------
__global__ __launch_bounds__(256) void k_gemm(
    const __hip_bfloat16* __restrict__ A, const __hip_bfloat16* __restrict__ Wb,
    _Float16* __restrict__ xlh) {
    const int lane = threadIdx.x & 63;
    const int wave = threadIdx.x >> 6;
    const int col = lane & 15;
    const int quad = lane >> 4;

    short8 bfrag[4][8];
    const short* wp = (const short*)Wb;
#pragma unroll
    for (int tt = 0; tt < 8; ++tt) {
        int row = tt * 16 + col;
#pragma unroll
        for (int kk = 0; kk < 4; ++kk)
            bfrag[kk][tt] = *(const short8*)(wp + row * 128 + kk * 32 + quad * 8);
    }
    int tile = blockIdx.x * 4 + wave;
    if (tile >= NN / 16) return;  // 3125 tiles
    int base = tile * 16;
    const short* xs = (const short*)A;

    floatx4 acc[8];
#pragma unroll
    for (int t = 0; t < 8; ++t) acc[t] = (floatx4){0.f, 0.f, 0.f, 0.f};
#pragma unroll
    for (int kk = 0; kk < 4; ++kk) {
        short8 afrag = *(const short8*)(xs + (size_t)(base + col) * 128 + kk * 32 + quad * 8);
#pragma unroll
        for (int tt = 0; tt < 8; ++tt)
            acc[tt] = __builtin_amdgcn_mfma_f32_16x16x32_bf16(afrag, bfrag[kk][tt], acc[tt], 0, 0, 0);
    }
#pragma unroll
    for (int tt = 0; tt < 8; ++tt) {
        int n = tt * 16 + col;
#pragma unroll
        for (int r = 0; r < 4; ++r) {
            int row = base + quad * 4 + r;
            xlh[(size_t)row * 128 + n] = (_Float16)acc[tt][r];
        }
    }
}

// ---------------- scatter core: wave per node, 4 edge-groups of 16 lanes ----------------
__device__ __forceinline__ void scatter_core(
    const int* __restrict__ rowptr, const int2* __restrict__ meta,
    const _Float16* __restrict__ xlh, int wid, int g, int c, float acc[8]) {
    int beg = rowptr[wid], end = rowptr[wid + 1];
    int p = beg + g;
    for (; p + 4 < end; p += 8) {
        int2 m1 = meta[p];
        int2 m2 = meta[p + 4];
        half8 r1 = *(const half8*)(xlh + (size_t)m1.x * 128 + c * 8);
        half8 r2 = *(const half8*)(xlh + (size_t)m2.x * 128 + c * 8);
        float c1 = __int_as_float(m1.y), c2 = __int_as_float(m2.y);
#pragma unroll
        for (int j = 0; j < 8; ++j) acc[j] += c1 * (float)r1[j] + c2 * (float)r2[j];
    }
    if (p < end) {
        int2 m1 = meta[p];
        half8 r1 = *(const half8*)(xlh + (size_t)m1.x * 128 + c * 8);
        float c1 = __int_as_float(m1.y);
#pragma unroll
        for (int j = 0; j < 8; ++j) acc[j] += c1 * (float)r1[j];
    }
#pragma unroll
    for (int j = 0; j < 8; ++j) {
        acc[j] += __shfl_xor(acc[j], 16, 64);
        acc[j] += __shfl_xor(acc[j], 32, 64);
    }
}

// mid-layer scatter: epilogue reconstructs bias + self-loop, emits relu as bf16
__global__ __launch_bounds__(256) void k_scatter_mid(
    const int* __restrict__ rowptr, const int2* __restrict__ meta,
    const float* __restrict__ deg, const _Float16* __restrict__ xlh,
    const float* __restrict__ bias, __hip_bfloat16* __restrict__ xb2) {
    int wid = (blockIdx.x * blockDim.x + threadIdx.x) >> 6;
    int lane = threadIdx.x & 63;
    if (wid >= NN) return;
    int g = lane >> 4, c = lane & 15;
    float acc[8] = {0.f, 0.f, 0.f, 0.f, 0.f, 0.f, 0.f, 0.f};
    scatter_core(rowptr, meta, xlh, wid, g, c, acc);
    if (g == 0) {
        float dn = rsqrtf(deg[wid]);
        float di2 = dn * dn;  // 1/deg: self-loop norm
        half8 sv = *(const half8*)(xlh + (size_t)wid * 128 + c * 8);
        const float4* bp = (const float4*)(bias + c * 8);
        float4 ba = bp[0], bb = bp[1];
        float bv[8] = {ba.x, ba.y, ba.z, ba.w, bb.x, bb.y, bb.z, bb.w};
        short8 o;
#pragma unroll
        for (int j = 0; j < 8; ++j) {
            float t = bv[j] + di2 * (float)sv[j] + dn * acc[j];
            t = t > 0.f ? t : 0.f;
            o[j] = bf16_bits(t);
        }
        *(short8*)((short*)xb2 + (size_t)wid * 128 + c * 8) = o;
    }
}

// final scatter fused with output head: sigmoid(relu(h2) @ Wlin^T + blin)
__global__ __launch_bounds__(256) void k_scatter_out(
    const int* __restrict__ rowptr, const int2* __restrict__ meta,
    const float* __restrict__ deg, const _Float16* __restrict__ xlh,
    const float* __restrict__ bias, const float* __restrict__ wlin,
    const float* __restrict__ blin, float* __restrict__ out) {
    int wid = (blockIdx.x * blockDim.x + threadIdx.x) >> 6;
    int lane = threadIdx.x & 63;
    if (wid >= NN) return;
    int g = lane >> 4, c = lane & 15;
    float acc[8] = {0.f, 0.f, 0.f, 0.f, 0.f, 0.f, 0.f, 0.f};
    scatter_core(rowptr, meta, xlh, wid, g, c, acc);
    if (g == 0) {
        float dn = rsqrtf(deg[wid]);
        float di2 = dn * dn;
        half8 sv = *(const half8*)(xlh + (size_t)wid * 128 + c * 8);
        const float4* bp = (const float4*)(bias + c * 8);
        float4 ba = bp[0], bb = bp[1];
        float bv[8] = {ba.x, ba.y, ba.z, ba.w, bb.x, bb.y, bb.z, bb.w};
        float p0 = 0.f, p1 = 0.f;
#pragma unroll
        for (int j = 0; j < 8; ++j) {
            float t = bv[j] + di2 * (float)sv[j] + dn * acc[j];
            t = t > 0.f ? t : 0.f;
            p0 += t * wlin[c * 8 + j];
            p1 += t * wlin[128 + c * 8 + j];
        }
#pragma unroll
        for (int off = 1; off < 16; off <<= 1) {
            p0 += __shfl_xor(p0, off, 64);
            p1 += __shfl_xor(p1, off, 64);
        }
        if (c == 0) {
            out[wid * 2 + 0] = 1.f / (1.f + __expf(-(p0 + blin[0])));
            out[wid * 2 + 1] = 1.f / (1.f + __expf(-(p1 + blin[1])));
        }
    }
}

// ---------------- host launcher ----------------

extern "C" void kernel_launch(void* const* d_in, const int* in_sizes, int n_in,
                              void* d_out, int out_size, void* d_ws, size_t ws_size,
                              hipStream_t stream) {
    const float* x = (const float*)d_in[0];
    const int* eidx_raw = (const int*)d_in[1];
    const float* W_p1 = (const float*)d_in[2];
    const float* b_p1 = (const float*)d_in[3];
    const float* W_p2 = (const float*)d_in[4];
    const float* b_p2 = (const float*)d_in[5];
    const float* W1 = (const float*)d_in[6];
    const float* b1 = (const float*)d_in[7];
    const float* W2 = (const float*)d_in[8];
    const float* b2 = (const float*)d_in[9];
    const float* W_lin = (const float*)d_in[10];
    const float* b_lin = (const float*)d_in[11];
    float* out = (float*)d_out;

    char* ws = (char*)d_ws;
    size_t off = 0;
    auto alloc = [&](size_t bytes) -> void* {
        off = (off + 255) & ~(size_t)255;
        void* p = ws + off;
        off += bytes;
        return p;
    };
    float* deg = (float*)alloc(NN * 4);
    int* rowptr = (int*)alloc((NN + 1) * 4);
    int* cursor = (int*)alloc(NN * 4);
    int* count = (int*)alloc(NN * 4);
    int* flag = (int*)alloc(4);
    int* bsums = (int*)alloc(128 * 4);
    int2* meta = (int2*)alloc((size_t)NE * 8);  // reused as scan tmp before fill
    __hip_bfloat16* xb = (__hip_bfloat16*)alloc((size_t)NN * 128 * 2);  // reused as xb2
    _Float16* xlh = (_Float16*)alloc((size_t)NN * 128 * 2);
    _Float16* uvh = (_Float16*)alloc((size_t)NN * 128 * 2);
    __hip_bfloat16* wcatb = (__hip_bfloat16*)alloc(128 * 128 * 2);
    __hip_bfloat16* w1b = (__hip_bfloat16*)alloc(128 * 128 * 2);
    __hip_bfloat16* w2b = (__hip_bfloat16*)alloc(128 * 128 * 2);
    int* tmp = (int*)meta;

    const int TB = 256;
    int gN = (NN + TB - 1) / TB;
    int gE = (NE + TB - 1) / TB;
    int gG = (NN / 16 + 3) / 4;
    int gS = (NN + 3) / 4;

    k_init<<<gN, TB, 0, stream>>>(eidx_raw, count, flag);
    k_count<<<gE, TB, 0, stream>>>(eidx_raw, flag, count);
    k_cvt_w<<<192, TB, 0, stream>>>(W_p1, W1, W2, wcatb, w1b, w2b);

    // uv = x @ Wcat^T (fp16, b1 folded into v); also emits xb (bf16 of x)
    k_gemm_uv<<<gG, TB, 0, stream>>>(x, wcatb, b_p1, uvh, xb);

    k_scan_block<<<98, 512, 0, stream>>>(count, tmp, bsums);
    k_scan_sums<<<1, 128, 0, stream>>>(bsums, 98);
    k_finalize_scan<<<gN, TB, 0, stream>>>(tmp, count, bsums, rowptr, cursor);
    k_fill<<<gE, TB, 0, stream>>>(eidx_raw, flag, cursor, meta);

    k_policy_csr<<<gS, TB, 0, stream>>>(uvh, W_p2, b_p2, rowptr, meta, deg);
    k_coef<<<gE, TB, 0, stream>>>(meta, deg);

    // layer 1
    k_gemm<<<gG, TB, 0, stream>>>(xb, w1b, xlh);
    k_scatter_mid<<<gS, TB, 0, stream>>>(rowptr, meta, deg, xlh, b1, xb);
    // layer 2
    k_gemm<<<gG, TB, 0, stream>>>(xb, w2b, xlh);
    k_scatter_out<<<gS, TB, 0, stream>>>(rowptr, meta, deg, xlh, b2, W_lin, b_lin, out);
}

// Round 5
// 297.045 us; speedup vs baseline: 2.0335x; 1.0693x over previous
//
#include <hip/hip_runtime.h>
#include <hip/hip_bf16.h>

#define NN 50000
#define NE 600000
// dims: in=128, hid=128, policy hidden=64, out=2

typedef __attribute__((ext_vector_type(8))) short short8;     // 8 bf16 (4 VGPRs)
typedef __attribute__((ext_vector_type(8))) _Float16 half8;   // 8 fp16
typedef __attribute__((ext_vector_type(4))) float floatx4;    // 4 f32 acc

__device__ __forceinline__ short bf16_bits(float v) {
    __hip_bfloat16 h = __float2bfloat16(v);
    return *reinterpret_cast<short*>(&h);
}

// ---------------- init: zero count + detect layout + convert weights ----------------
__global__ void k_init_cvt(const int* __restrict__ raw, int* __restrict__ count,
                           int* __restrict__ flag, const float* __restrict__ wp1,
                           const float* __restrict__ w1, const float* __restrict__ w2,
                           __hip_bfloat16* __restrict__ wcatb, __hip_bfloat16* __restrict__ w1b,
                           __hip_bfloat16* __restrict__ w2b) {
    int i = blockIdx.x * blockDim.x + threadIdx.x;
    if (i < NN) count[i] = 0;
    if (i < 16384) {
        int r = i >> 7, c = i & 127;
        float v = (r < 64) ? wp1[r * 256 + c] : wp1[(r - 64) * 256 + 128 + c];
        wcatb[i] = __float2bfloat16(v);
    } else if (i < 32768) {
        w1b[i - 16384] = __float2bfloat16(w1[i - 16384]);
    } else if (i < 49152) {
        w2b[i - 32768] = __float2bfloat16(w2[i - 32768]);
    }
    if (blockIdx.x == 0) {
        if (threadIdx.x == 0) *flag = 0;
        __syncthreads();
        int any = 0;
        for (int j = threadIdx.x; j < 1024; j += 256) any |= raw[2 * j + 1];
        if (any) atomicOr(flag, 1);  // flag=1 -> int32 layout
    }
}

// ---------------- merged: gemm_uv (blocks < gG) + degree count (rest) ----------------
// uv = x @ Wcat^T (fp16, b_p1 folded into v half); also emits xb (bf16 of x)
#define GG 782  // ceil(3125/4)
__global__ __launch_bounds__(256) void k_uv_count(
    const float* __restrict__ x, const __hip_bfloat16* __restrict__ Wb,
    const float* __restrict__ bp1, _Float16* __restrict__ uvh,
    __hip_bfloat16* __restrict__ xb, const int* __restrict__ raw,
    const int* __restrict__ flag, int* __restrict__ count) {
    if (blockIdx.x >= GG) {
        int e = (blockIdx.x - GG) * blockDim.x + threadIdx.x;
        if (e < NE) {
            int d = (*flag) ? raw[NE + e] : (int)((const long long*)raw)[NE + e];
            atomicAdd(&count[d], 1);
        }
        return;
    }
    const int lane = threadIdx.x & 63;
    const int wave = threadIdx.x >> 6;
    const int col = lane & 15;
    const int quad = lane >> 4;

    short8 bfrag[4][8];
    const short* wp = (const short*)Wb;
#pragma unroll
    for (int tt = 0; tt < 8; ++tt) {
        int row = tt * 16 + col;
#pragma unroll
        for (int kk = 0; kk < 4; ++kk)
            bfrag[kk][tt] = *(const short8*)(wp + row * 128 + kk * 32 + quad * 8);
    }
    int tile = blockIdx.x * 4 + wave;
    if (tile >= NN / 16) return;
    int base = tile * 16;

    floatx4 acc[8];
#pragma unroll
    for (int t = 0; t < 8; ++t) acc[t] = (floatx4){0.f, 0.f, 0.f, 0.f};
#pragma unroll
    for (int kk = 0; kk < 4; ++kk) {
        const float* xrow = x + (size_t)(base + col) * 128 + kk * 32 + quad * 8;
        float4 f0 = ((const float4*)xrow)[0];
        float4 f1 = ((const float4*)xrow)[1];
        short8 afrag;
        afrag[0] = bf16_bits(f0.x); afrag[1] = bf16_bits(f0.y);
        afrag[2] = bf16_bits(f0.z); afrag[3] = bf16_bits(f0.w);
        afrag[4] = bf16_bits(f1.x); afrag[5] = bf16_bits(f1.y);
        afrag[6] = bf16_bits(f1.z); afrag[7] = bf16_bits(f1.w);
        *(short8*)((short*)xb + (size_t)(base + col) * 128 + kk * 32 + quad * 8) = afrag;
#pragma unroll
        for (int tt = 0; tt < 8; ++tt)
            acc[tt] = __builtin_amdgcn_mfma_f32_16x16x32_bf16(afrag, bfrag[kk][tt], acc[tt], 0, 0, 0);
    }
#pragma unroll
    for (int tt = 0; tt < 8; ++tt) {
        int n = tt * 16 + col;
        float badd = (tt >= 4) ? bp1[n - 64] : 0.f;
#pragma unroll
        for (int r = 0; r < 4; ++r) {
            int row = base + quad * 4 + r;
            uvh[(size_t)row * 128 + n] = (_Float16)(acc[tt][r] + badd);
        }
    }
}

// block-level inclusive scan of count[NN] (512/block)
__global__ void k_scan_block(const int* __restrict__ count, int* __restrict__ tmp,
                             int* __restrict__ bsums) {
    __shared__ int s[512];
    int tid = threadIdx.x;
    int i = blockIdx.x * 512 + tid;
    s[tid] = (i < NN) ? count[i] : 0;
    __syncthreads();
    for (int off = 1; off < 512; off <<= 1) {
        int t = (tid >= off) ? s[tid - off] : 0;
        __syncthreads();
        s[tid] += t;
        __syncthreads();
    }
    if (i < NN) tmp[i] = s[tid];
    if (tid == 511) bsums[blockIdx.x] = s[511];
}

// finalize: each block re-scans the 98 block sums in LDS (cheap), builds rowptr/cursor
__global__ void k_finalize(const int* __restrict__ tmp, const int* __restrict__ count,
                           const int* __restrict__ bsums, int* __restrict__ rowptr,
                           int* __restrict__ cursor) {
    __shared__ int sb[128];
    int tid = threadIdx.x;
    if (tid < 128) sb[tid] = (tid < 98) ? bsums[tid] : 0;
    __syncthreads();
    for (int off = 1; off < 128; off <<= 1) {
        int t = (tid < 128 && tid >= off) ? sb[tid - off] : 0;
        __syncthreads();
        if (tid < 128) sb[tid] += t;
        __syncthreads();
    }
    int i = blockIdx.x * blockDim.x + tid;
    if (i >= NN) return;
    int blk = i >> 9;
    int add = blk ? sb[blk - 1] : 0;
    int incl = tmp[i] + add;
    rowptr[i + 1] = incl;
    cursor[i] = incl - count[i];
    if (i == 0) rowptr[0] = 0;
}

// CSR fill from raw edges: meta[pos] = {src, junk} (policy fills .y)
__global__ void k_fill(const int* __restrict__ raw, const int* __restrict__ flag,
                       int* __restrict__ cursor, int2* __restrict__ meta) {
    int e = blockIdx.x * blockDim.x + threadIdx.x;
    if (e >= NE) return;
    int s, d;
    if (*flag) {
        s = raw[e];
        d = raw[NE + e];
    } else {
        const long long* r64 = (const long long*)raw;
        s = (int)r64[e];
        d = (int)r64[NE + e];
    }
    int pos = atomicAdd(&cursor[d], 1);
    meta[pos] = make_int2(s, 0);
}

// ---------------- policy MLP in CSR order: wave per dst node ----------------
// v[dst] loaded once; per in-edge gather u[src]; ew -> meta.y; deg w/o atomics
__global__ __launch_bounds__(256) void k_policy_csr(
    const _Float16* __restrict__ uvh, const float* __restrict__ wp2,
    const float* __restrict__ bp2, const int* __restrict__ rowptr,
    int2* __restrict__ meta, float* __restrict__ deg) {
    int wid = (blockIdx.x * blockDim.x + threadIdx.x) >> 6;
    int lane = threadIdx.x & 63;
    if (wid >= NN) return;
    int g = lane >> 3, c = lane & 7;  // 8 edge-groups of 8 lanes
    half8 vh = *(const half8*)(uvh + (size_t)wid * 128 + 64 + c * 8);
    float vv[8], w2v[8];
    const float4* w2p = (const float4*)(wp2 + c * 8);
    float4 wa = w2p[0], wb = w2p[1];
    w2v[0] = wa.x; w2v[1] = wa.y; w2v[2] = wa.z; w2v[3] = wa.w;
    w2v[4] = wb.x; w2v[5] = wb.y; w2v[6] = wb.z; w2v[7] = wb.w;
#pragma unroll
    for (int j = 0; j < 8; ++j) vv[j] = (float)vh[j];
    float b2 = bp2[0];
    int beg = rowptr[wid], end = rowptr[wid + 1];
    float degsum = 0.f;
    int p = beg + g;
    for (; p + 8 < end; p += 16) {  // unroll 2: two edges in flight per group
        int s1 = meta[p].x, s2 = meta[p + 8].x;
        half8 u1 = *(const half8*)(uvh + (size_t)s1 * 128 + c * 8);
        half8 u2 = *(const half8*)(uvh + (size_t)s2 * 128 + c * 8);
        float p1 = 0.f, p2 = 0.f;
#pragma unroll
        for (int j = 0; j < 8; ++j) {
            float h1 = (float)u1[j] + vv[j];
            float h2 = (float)u2[j] + vv[j];
            h1 = h1 > 0.f ? h1 : 0.f;
            h2 = h2 > 0.f ? h2 : 0.f;
            p1 += h1 * w2v[j];
            p2 += h2 * w2v[j];
        }
        p1 += __shfl_xor(p1, 1, 64); p2 += __shfl_xor(p2, 1, 64);
        p1 += __shfl_xor(p1, 2, 64); p2 += __shfl_xor(p2, 2, 64);
        p1 += __shfl_xor(p1, 4, 64); p2 += __shfl_xor(p2, 4, 64);
        if (c == 0) {
            float e1 = 1.f / (1.f + __expf(-(p1 + b2)));
            float e2 = 1.f / (1.f + __expf(-(p2 + b2)));
            meta[p].y = __float_as_int(e1);
            meta[p + 8].y = __float_as_int(e2);
            degsum += e1 + e2;
        }
    }
    if (p < end) {
        int s1 = meta[p].x;
        half8 u1 = *(const half8*)(uvh + (size_t)s1 * 128 + c * 8);
        float p1 = 0.f;
#pragma unroll
        for (int j = 0; j < 8; ++j) {
            float h1 = (float)u1[j] + vv[j];
            h1 = h1 > 0.f ? h1 : 0.f;
            p1 += h1 * w2v[j];
        }
        p1 += __shfl_xor(p1, 1, 64);
        p1 += __shfl_xor(p1, 2, 64);
        p1 += __shfl_xor(p1, 4, 64);
        if (c == 0) {
            float e1 = 1.f / (1.f + __expf(-(p1 + b2)));
            meta[p].y = __float_as_int(e1);
            degsum += e1;
        }
    }
    degsum += __shfl_xor(degsum, 8, 64);
    degsum += __shfl_xor(degsum, 16, 64);
    degsum += __shfl_xor(degsum, 32, 64);
    if (lane == 0) deg[wid] = 1.f + degsum;
}

// ---------------- GCN feature transform: xl' = dinv * (A_in @ W^T) (fp16) ----------------
__global__ __launch_bounds__(256) void k_gemm(
    const __hip_bfloat16* __restrict__ A, const __hip_bfloat16* __restrict__ Wb,
    const float* __restrict__ deg, _Float16* __restrict__ xlh) {
    const int lane = threadIdx.x & 63;
    const int wave = threadIdx.x >> 6;
    const int col = lane & 15;
    const int quad = lane >> 4;

    short8 bfrag[4][8];
    const short* wp = (const short*)Wb;
#pragma unroll
    for (int tt = 0; tt < 8; ++tt) {
        int row = tt * 16 + col;
#pragma unroll
        for (int kk = 0; kk < 4; ++kk)
            bfrag[kk][tt] = *(const short8*)(wp + row * 128 + kk * 32 + quad * 8);
    }
    int tile = blockIdx.x * 4 + wave;
    if (tile >= NN / 16) return;  // 3125 tiles
    int base = tile * 16;
    const short* xs = (const short*)A;

    floatx4 acc[8];
#pragma unroll
    for (int t = 0; t < 8; ++t) acc[t] = (floatx4){0.f, 0.f, 0.f, 0.f};
#pragma unroll
    for (int kk = 0; kk < 4; ++kk) {
        short8 afrag = *(const short8*)(xs + (size_t)(base + col) * 128 + kk * 32 + quad * 8);
#pragma unroll
        for (int tt = 0; tt < 8; ++tt)
            acc[tt] = __builtin_amdgcn_mfma_f32_16x16x32_bf16(afrag, bfrag[kk][tt], acc[tt], 0, 0, 0);
    }
    float di[4];
#pragma unroll
    for (int r = 0; r < 4; ++r) di[r] = rsqrtf(deg[base + quad * 4 + r]);
#pragma unroll
    for (int tt = 0; tt < 8; ++tt) {
        int n = tt * 16 + col;
#pragma unroll
        for (int r = 0; r < 4; ++r) {
            int row = base + quad * 4 + r;
            xlh[(size_t)row * 128 + n] = (_Float16)(di[r] * acc[tt][r]);
        }
    }
}

// ---------------- scatter core: wave per node, 4 edge-groups of 16 lanes ----------------
// xlh is pre-scaled by dinv[src]; coef = ew (meta.y)
__device__ __forceinline__ void scatter_core(
    const int* __restrict__ rowptr, const int2* __restrict__ meta,
    const _Float16* __restrict__ xlh, int wid, int g, int c, float acc[8]) {
    int beg = rowptr[wid], end = rowptr[wid + 1];
    int p = beg + g;
    for (; p + 12 < end; p += 16) {
        int2 m1 = meta[p], m2 = meta[p + 4], m3 = meta[p + 8], m4 = meta[p + 12];
        half8 r1 = *(const half8*)(xlh + (size_t)m1.x * 128 + c * 8);
        half8 r2 = *(const half8*)(xlh + (size_t)m2.x * 128 + c * 8);
        half8 r3 = *(const half8*)(xlh + (size_t)m3.x * 128 + c * 8);
        half8 r4 = *(const half8*)(xlh + (size_t)m4.x * 128 + c * 8);
        float c1 = __int_as_float(m1.y), c2 = __int_as_float(m2.y);
        float c3 = __int_as_float(m3.y), c4 = __int_as_float(m4.y);
#pragma unroll
        for (int j = 0; j < 8; ++j)
            acc[j] += c1 * (float)r1[j] + c2 * (float)r2[j] + c3 * (float)r3[j] + c4 * (float)r4[j];
    }
    for (; p + 4 < end; p += 8) {
        int2 m1 = meta[p], m2 = meta[p + 4];
        half8 r1 = *(const half8*)(xlh + (size_t)m1.x * 128 + c * 8);
        half8 r2 = *(const half8*)(xlh + (size_t)m2.x * 128 + c * 8);
        float c1 = __int_as_float(m1.y), c2 = __int_as_float(m2.y);
#pragma unroll
        for (int j = 0; j < 8; ++j) acc[j] += c1 * (float)r1[j] + c2 * (float)r2[j];
    }
    if (p < end) {
        int2 m1 = meta[p];
        half8 r1 = *(const half8*)(xlh + (size_t)m1.x * 128 + c * 8);
        float c1 = __int_as_float(m1.y);
#pragma unroll
        for (int j = 0; j < 8; ++j) acc[j] += c1 * (float)r1[j];
    }
#pragma unroll
    for (int j = 0; j < 8; ++j) {
        acc[j] += __shfl_xor(acc[j], 16, 64);
        acc[j] += __shfl_xor(acc[j], 32, 64);
    }
}

// mid-layer scatter: epilogue reconstructs bias + self-loop, emits relu as bf16
__global__ __launch_bounds__(256) void k_scatter_mid(
    const int* __restrict__ rowptr, const int2* __restrict__ meta,
    const float* __restrict__ deg, const _Float16* __restrict__ xlh,
    const float* __restrict__ bias, __hip_bfloat16* __restrict__ xb2) {
    int wid = (blockIdx.x * blockDim.x + threadIdx.x) >> 6;
    int lane = threadIdx.x & 63;
    if (wid >= NN) return;
    int g = lane >> 4, c = lane & 15;
    float acc[8] = {0.f, 0.f, 0.f, 0.f, 0.f, 0.f, 0.f, 0.f};
    scatter_core(rowptr, meta, xlh, wid, g, c, acc);
    if (g == 0) {
        float dn = rsqrtf(deg[wid]);
        half8 sv = *(const half8*)(xlh + (size_t)wid * 128 + c * 8);  // pre-scaled self row
        const float4* bp = (const float4*)(bias + c * 8);
        float4 ba = bp[0], bb = bp[1];
        float bv[8] = {ba.x, ba.y, ba.z, ba.w, bb.x, bb.y, bb.z, bb.w};
        short8 o;
#pragma unroll
        for (int j = 0; j < 8; ++j) {
            float t = bv[j] + dn * ((float)sv[j] + acc[j]);
            t = t > 0.f ? t : 0.f;
            o[j] = bf16_bits(t);
        }
        *(short8*)((short*)xb2 + (size_t)wid * 128 + c * 8) = o;
    }
}

// final scatter fused with output head: sigmoid(relu(h2) @ Wlin^T + blin)
__global__ __launch_bounds__(256) void k_scatter_out(
    const int* __restrict__ rowptr, const int2* __restrict__ meta,
    const float* __restrict__ deg, const _Float16* __restrict__ xlh,
    const float* __restrict__ bias, const float* __restrict__ wlin,
    const float* __restrict__ blin, float* __restrict__ out) {
    int wid = (blockIdx.x * blockDim.x + threadIdx.x) >> 6;
    int lane = threadIdx.x & 63;
    if (wid >= NN) return;
    int g = lane >> 4, c = lane & 15;
    float acc[8] = {0.f, 0.f, 0.f, 0.f, 0.f, 0.f, 0.f, 0.f};
    scatter_core(rowptr, meta, xlh, wid, g, c, acc);
    if (g == 0) {
        float dn = rsqrtf(deg[wid]);
        half8 sv = *(const half8*)(xlh + (size_t)wid * 128 + c * 8);
        const float4* bp = (const float4*)(bias + c * 8);
        float4 ba = bp[0], bb = bp[1];
        float bv[8] = {ba.x, ba.y, ba.z, ba.w, bb.x, bb.y, bb.z, bb.w};
        float p0 = 0.f, p1 = 0.f;
#pragma unroll
        for (int j = 0; j < 8; ++j) {
            float t = bv[j] + dn * ((float)sv[j] + acc[j]);
            t = t > 0.f ? t : 0.f;
            p0 += t * wlin[c * 8 + j];
            p1 += t * wlin[128 + c * 8 + j];
        }
#pragma unroll
        for (int off = 1; off < 16; off <<= 1) {
            p0 += __shfl_xor(p0, off, 64);
            p1 += __shfl_xor(p1, off, 64);
        }
        if (c == 0) {
            out[wid * 2 + 0] = 1.f / (1.f + __expf(-(p0 + blin[0])));
            out[wid * 2 + 1] = 1.f / (1.f + __expf(-(p1 + blin[1])));
        }
    }
}

// ---------------- host launcher ----------------

extern "C" void kernel_launch(void* const* d_in, const int* in_sizes, int n_in,
                              void* d_out, int out_size, void* d_ws, size_t ws_size,
                              hipStream_t stream) {
    const float* x = (const float*)d_in[0];
    const int* eidx_raw = (const int*)d_in[1];
    const float* W_p1 = (const float*)d_in[2];
    const float* b_p1 = (const float*)d_in[3];
    const float* W_p2 = (const float*)d_in[4];
    const float* b_p2 = (const float*)d_in[5];
    const float* W1 = (const float*)d_in[6];
    const float* b1 = (const float*)d_in[7];
    const float* W2 = (const float*)d_in[8];
    const float* b2 = (const float*)d_in[9];
    const float* W_lin = (const float*)d_in[10];
    const float* b_lin = (const float*)d_in[11];
    float* out = (float*)d_out;

    char* ws = (char*)d_ws;
    size_t off = 0;
    auto alloc = [&](size_t bytes) -> void* {
        off = (off + 255) & ~(size_t)255;
        void* p = ws + off;
        off += bytes;
        return p;
    };
    float* deg = (float*)alloc(NN * 4);
    int* rowptr = (int*)alloc((NN + 1) * 4);
    int* cursor = (int*)alloc(NN * 4);
    int* count = (int*)alloc(NN * 4);
    int* flag = (int*)alloc(4);
    int* bsums = (int*)alloc(128 * 4);
    int2* meta = (int2*)alloc((size_t)NE * 8);  // reused as scan tmp before fill
    __hip_bfloat16* xb = (__hip_bfloat16*)alloc((size_t)NN * 128 * 2);  // reused as xb2
    _Float16* xlh = (_Float16*)alloc((size_t)NN * 128 * 2);
    _Float16* uvh = (_Float16*)alloc((size_t)NN * 128 * 2);
    __hip_bfloat16* wcatb = (__hip_bfloat16*)alloc(128 * 128 * 2);
    __hip_bfloat16* w1b = (__hip_bfloat16*)alloc(128 * 128 * 2);
    __hip_bfloat16* w2b = (__hip_bfloat16*)alloc(128 * 128 * 2);
    int* tmp = (int*)meta;

    const int TB = 256;
    int gN = (NN + TB - 1) / TB;       // 196
    int gE = (NE + TB - 1) / TB;       // 2344
    int gS = (NN + 3) / 4;             // 12500

    k_init_cvt<<<gN, TB, 0, stream>>>(eidx_raw, count, flag, W_p1, W1, W2, wcatb, w1b, w2b);
    // merged: uv-gemm + degree count
    k_uv_count<<<GG + gE, TB, 0, stream>>>(x, wcatb, b_p1, uvh, xb, eidx_raw, flag, count);

    k_scan_block<<<98, 512, 0, stream>>>(count, tmp, bsums);
    k_finalize<<<gN, TB, 0, stream>>>(tmp, count, bsums, rowptr, cursor);
    k_fill<<<gE, TB, 0, stream>>>(eidx_raw, flag, cursor, meta);

    k_policy_csr<<<gS, TB, 0, stream>>>(uvh, W_p2, b_p2, rowptr, meta, deg);

    // layer 1 (dinv folded into xlh)
    k_gemm<<<GG, TB, 0, stream>>>(xb, w1b, deg, xlh);
    k_scatter_mid<<<gS, TB, 0, stream>>>(rowptr, meta, deg, xlh, b1, xb);
    // layer 2
    k_gemm<<<GG, TB, 0, stream>>>(xb, w2b, deg, xlh);
    k_scatter_out<<<gS, TB, 0, stream>>>(rowptr, meta, deg, xlh, b2, W_lin, b_lin, out);
}